// Round 13
// baseline (429.920 us; speedup 1.0000x reference)
//
#include <hip/hip_runtime.h>
#include <hip/hip_bf16.h>

typedef unsigned short ushort;
typedef __attribute__((ext_vector_type(8))) __bf16 bf16x8;
typedef __attribute__((ext_vector_type(4))) float f32x4;
typedef __attribute__((ext_vector_type(8))) ushort ushort8;

__device__ inline ushort f2bf(float f) {
    union { float f; unsigned u; } a{f};
    unsigned r = a.u + 0x7FFFu + ((a.u >> 16) & 1u);
    return (ushort)(r >> 16);
}
__device__ inline float gelu_f(float x) {
    return 0.5f * x * (1.f + erff(x * 0.70710678118654752f));
}

// ---------------- transpose weight [K,N] fp32 -> [N,K] bf16 ----------------
__global__ void transpose_to_bf16(const float* __restrict__ Wm, ushort* __restrict__ Wt, int K, int N) {
    __shared__ float tile[32][33];
    int k0 = blockIdx.x * 32, n0 = blockIdx.y * 32;
    int tx = threadIdx.x, ty = threadIdx.y;
    #pragma unroll
    for (int r = ty; r < 32; r += 8) tile[r][tx] = Wm[(size_t)(k0 + r) * N + n0 + tx];
    __syncthreads();
    #pragma unroll
    for (int r = ty; r < 32; r += 8) Wt[(size_t)(n0 + r) * K + k0 + tx] = f2bf(tile[tx][r]);
}

// ---------------- row stats: xb (bf16 copy) + sq (sum of squares) ----------
__global__ void rowstat(const float* __restrict__ x, ushort* __restrict__ xb, float* __restrict__ sq) {
    int row = blockIdx.x;
    const float* xr = x + (size_t)row * 768;
    ushort* xbr = xb + (size_t)row * 768;
    int t = threadIdx.x;
    float s = 0.f;
    #pragma unroll
    for (int i = 0; i < 3; ++i) {
        float vv = xr[t + i * 256];
        xbr[t + i * 256] = f2bf(vv);
        s += vv * vv;
    }
    #pragma unroll
    for (int off = 1; off < 64; off <<= 1) s += __shfl_xor(s, off);
    __shared__ float wsum[4];
    if ((t & 63) == 0) wsum[t >> 6] = s;
    __syncthreads();
    if (t == 0) sq[row] = wsum[0] + wsum[1] + wsum[2] + wsum[3];
}

// ---------------- fold dp/se_w1 into rank-1 vectors ------------------------
__global__ void precomp_ac(const float* __restrict__ dp_w, const float* __restrict__ dp_b,
                           const float* __restrict__ se_w1, const float* __restrict__ se_b1,
                           float* __restrict__ Avec, float* __restrict__ Cvec) {
    int o = blockIdx.x * 256 + threadIdx.x;  // grid 3 -> 768
    float a = 0.f, c = 0.f;
    for (int i = 0; i < 192; ++i) {
        float w = se_w1[(size_t)i * 768 + o];
        a += dp_w[i] * w;
        c += dp_b[i] * w;
    }
    Avec[o] = a;
    Cvec[o] = c + se_b1[o];
}

// ---------------- spatial h generation (rank-1 + gelu) ---------------------
__global__ void hgen(const float* __restrict__ mean_acc, const float* __restrict__ Avec,
                     const float* __restrict__ Cvec, ushort* __restrict__ h) {
    int row = blockIdx.x;
    float md = mean_acc[row] * (1.f / 1024.f);
    int t = threadIdx.x;
    #pragma unroll
    for (int i = 0; i < 3; ++i) {
        int o = t + i * 256;
        h[(size_t)row * 768 + o] = f2bf(gelu_f(md * Avec[o] + Cvec[o]));
    }
}

// ---------------- layernorm fp32 -> bf16 -----------------------------------
__global__ void lnorm(const float* __restrict__ xin, const float* __restrict__ g,
                      const float* __restrict__ b, ushort* __restrict__ xn) {
    int row = blockIdx.x;
    const float* xr = xin + (size_t)row * 768;
    int t = threadIdx.x;
    float v[3];
    float s = 0.f, s2 = 0.f;
    #pragma unroll
    for (int i = 0; i < 3; ++i) {
        v[i] = xr[t + i * 256];
        s += v[i];
        s2 += v[i] * v[i];
    }
    #pragma unroll
    for (int off = 1; off < 64; off <<= 1) { s += __shfl_xor(s, off); s2 += __shfl_xor(s2, off); }
    __shared__ float a0[4], a1[4];
    if ((t & 63) == 0) { a0[t >> 6] = s; a1[t >> 6] = s2; }
    __syncthreads();
    s = a0[0] + a0[1] + a0[2] + a0[3];
    s2 = a1[0] + a1[1] + a1[2] + a1[3];
    float mu = s * (1.f / 768.f);
    float var = s2 * (1.f / 768.f) - mu * mu;
    float rs = rsqrtf(var + 1e-5f);
    #pragma unroll
    for (int i = 0; i < 3; ++i) {
        int o = t + i * 256;
        xn[(size_t)row * 768 + o] = f2bf((v[i] - mu) * rs * g[o] + b[o]);
    }
}

// ---------------- MFMA GEMM (2-phase, 128-tile): used for Gram only --------
#define BM 128
#define BK 32

enum { EPI_BF16 = 0, EPI_GELU = 1, EPI_RES = 2, EPI_GRAM = 3, EPI_QKV = 4, EPI_RESK = 5 };

template <int EPI, int BNT>
__launch_bounds__(256, BNT == 64 ? 4 : 2)
__global__ void gemm_bt(const ushort* __restrict__ A, const ushort* __restrict__ Bt,
                        int M, int N, int K,
                        const float* __restrict__ bias,
                        const float* res, float* outf,
                        ushort* __restrict__ outh,
                        const float* __restrict__ sq, float* __restrict__ mean_acc) {
    __shared__ __align__(16) ushort As[2][BM * BK];
    __shared__ __align__(16) ushort Bs[2][BNT * BK];

    unsigned gx = gridDim.x, gy = gridDim.y;
    unsigned flat = blockIdx.x + gx * (blockIdx.y + gy * blockIdx.z);
    unsigned total = gx * gy * gridDim.z;
    unsigned chunk = total >> 3;
    flat = (flat & 7) * chunk + (flat >> 3);
    unsigned bx = flat % gx;
    unsigned rem = flat / gx;
    unsigned by = rem % gy;
    unsigned bz = rem / gy;

    int m0 = bx * BM;
    int n0 = by * BNT;
    if (EPI == EPI_GRAM) {
        A += (size_t)bz * 1024 * 768;
        Bt = A;
        sq += bz * 1024;
        mean_acc += bz * 1024;
    }
    int t = threadIdx.x, w = t >> 6, l = t & 63;
    int lg = l >> 4, li = l & 15;
    constexpr int MI = (BNT == 128) ? 4 : 2;
    int wm = (BNT == 128) ? (w >> 1) * 64 : w * 32;
    int wn = (BNT == 128) ? (w & 1) * 64 : 0;

    int srow = l >> 2, scol = (l & 3) * 8;
    const ushort* agp0 = A + (size_t)(m0 + (2 * w) * 16 + srow) * K + scol;
    const ushort* agp1 = A + (size_t)(m0 + (2 * w + 1) * 16 + srow) * K + scol;
    const ushort* bgp0;
    const ushort* bgp1 = nullptr;
    ushort* la0 = &As[0][(2 * w) * 16 * BK];
    ushort* lb0;
    if (BNT == 128) {
        bgp0 = Bt + (size_t)(n0 + (2 * w) * 16 + srow) * K + scol;
        bgp1 = Bt + (size_t)(n0 + (2 * w + 1) * 16 + srow) * K + scol;
        lb0 = &Bs[0][(2 * w) * 16 * BK];
    } else {
        bgp0 = Bt + (size_t)(n0 + w * 16 + srow) * K + scol;
        lb0 = &Bs[0][w * 16 * BK];
    }

    f32x4 acc[MI][4] = {};

    auto stage = [&](int buf, int kt) {
        size_t ko = (size_t)kt * BK;
        ushort* la = la0 + buf * (BM * BK);
        ushort* lb = lb0 + buf * (BNT * BK);
        __builtin_amdgcn_global_load_lds((const __attribute__((address_space(1))) void*)(agp0 + ko),
                                         (__attribute__((address_space(3))) void*)la, 16, 0, 0);
        __builtin_amdgcn_global_load_lds((const __attribute__((address_space(1))) void*)(agp1 + ko),
                                         (__attribute__((address_space(3))) void*)(la + 16 * BK), 16, 0, 0);
        __builtin_amdgcn_global_load_lds((const __attribute__((address_space(1))) void*)(bgp0 + ko),
                                         (__attribute__((address_space(3))) void*)lb, 16, 0, 0);
        if (BNT == 128)
            __builtin_amdgcn_global_load_lds((const __attribute__((address_space(1))) void*)(bgp1 + ko),
                                             (__attribute__((address_space(3))) void*)(lb + 16 * BK), 16, 0, 0);
    };

    int nk = K / BK;
    stage(0, 0);
    __syncthreads();
    int buf = 0;
    for (int kt = 0; kt < nk; ++kt) {
        if (kt + 1 < nk) stage(buf ^ 1, kt + 1);
        bf16x8 af[MI], bfr[4];
        #pragma unroll
        for (int i = 0; i < MI; ++i)
            af[i] = *reinterpret_cast<const bf16x8*>(&As[buf][(wm + i * 16 + li) * BK + lg * 8]);
        #pragma unroll
        for (int i = 0; i < 4; ++i)
            bfr[i] = *reinterpret_cast<const bf16x8*>(&Bs[buf][(wn + i * 16 + li) * BK + lg * 8]);
        #pragma unroll
        for (int mi = 0; mi < MI; ++mi)
            #pragma unroll
            for (int ni = 0; ni < 4; ++ni)
                acc[mi][ni] = __builtin_amdgcn_mfma_f32_16x16x32_bf16(af[mi], bfr[ni], acc[mi][ni], 0, 0, 0);
        __syncthreads();
        buf ^= 1;
    }

    #pragma unroll
    for (int mi = 0; mi < MI; ++mi) {
        #pragma unroll
        for (int r = 0; r < 4; ++r) {
            int row = m0 + wm + mi * 16 + lg * 4 + r;
            if (EPI == EPI_GRAM) {
                float si = sq[row];
                float s = 0.f;
                #pragma unroll
                for (int ni = 0; ni < 4; ++ni) {
                    int col = n0 + wn + ni * 16 + li;
                    float d2 = si + sq[col] - 2.f * acc[mi][ni][r];
                    s += sqrtf(fmaxf(d2, 0.f));
                }
                s += __shfl_xor(s, 1); s += __shfl_xor(s, 2);
                s += __shfl_xor(s, 4); s += __shfl_xor(s, 8);
                if (li == 0) atomicAdd(&mean_acc[row], s);
            } else {
                #pragma unroll
                for (int ni = 0; ni < 4; ++ni) {
                    int col = n0 + wn + ni * 16 + li;
                    float v = acc[mi][ni][r] + bias[col];
                    if (EPI == EPI_BF16) outh[(size_t)row * N + col] = f2bf(v);
                    if (EPI == EPI_GELU) outh[(size_t)row * N + col] = f2bf(gelu_f(v));
                    if (EPI == EPI_RES) outf[(size_t)row * N + col] = res[(size_t)row * N + col] + v;
                    if (EPI == EPI_QKV) {
                        int which = col / 768;
                        int c2 = col - which * 768;
                        outh[(size_t)which * (8192 * 768) + (size_t)row * 768 + c2] = f2bf(v);
                    }
                }
            }
        }
    }
}

// ---------------- gemm4: m97-structure 128x128, m-split XCD, 3 blocks/CU ---
// 4 waves, BK=32, 32 KB LDS, double-buffered global_load_lds. Cross-block
// overlap (m114) covers barrier drains. EPI_RESK: split-K=2 via gridDim.z=2,
// fp32 atomicAdd onto outf (which already holds the residual); bias added by
// split 0 only. L3 absorbs cross-XCD B reuse (measured r11/r12: FETCH=A+B).
template <int EPI>
__launch_bounds__(256, 3)
__global__ void gemm4(const ushort* __restrict__ A, const ushort* __restrict__ Bt,
                      int M, int N, int K,
                      const float* __restrict__ bias,
                      const float* res, float* outf, ushort* __restrict__ outh) {
    __shared__ __align__(16) ushort As[2][128 * 32];
    __shared__ __align__(16) ushort Bs[2][128 * 32];

    // m-split: xcd owns gx/8 m-tiles x all (n, split); m fastest -> A L2-resident
    unsigned gx = gridDim.x, gy = gridDim.y;
    unsigned orig = blockIdx.x + gx * (blockIdx.y + gy * blockIdx.z);
    unsigned xcd = orig & 7;
    unsigned q = orig >> 3;
    unsigned mpg = gx >> 3;
    unsigned mloc = q % mpg;
    unsigned rest = q / mpg;
    unsigned n = rest % gy;
    unsigned split = rest / gy;              // 0 unless gridDim.z == 2
    int m0 = (xcd * mpg + mloc) * 128;
    int n0 = n * 128;
    int Keff = (EPI == EPI_RESK) ? (K >> 1) : K;
    int kbase = (EPI == EPI_RESK) ? (int)split * Keff : 0;

    int t = threadIdx.x, w = t >> 6, l = t & 63;
    int lg = l >> 4, li = l & 15;
    int wm = (w >> 1) * 64, wn = (w & 1) * 64;

    int srow = l >> 2, scol = (l & 3) * 8;
    const ushort* agp0 = A + (size_t)(m0 + (2 * w) * 16 + srow) * K + kbase + scol;
    const ushort* agp1 = A + (size_t)(m0 + (2 * w + 1) * 16 + srow) * K + kbase + scol;
    const ushort* bgp0 = Bt + (size_t)(n0 + (2 * w) * 16 + srow) * K + kbase + scol;
    const ushort* bgp1 = Bt + (size_t)(n0 + (2 * w + 1) * 16 + srow) * K + kbase + scol;
    ushort* la0 = &As[0][(2 * w) * 16 * 32];
    ushort* lb0 = &Bs[0][(2 * w) * 16 * 32];

    f32x4 acc[4][4] = {};

    auto stage = [&](int buf, int kt) {
        size_t ko = (size_t)kt * 32;
        ushort* la = la0 + buf * (128 * 32);
        ushort* lb = lb0 + buf * (128 * 32);
        __builtin_amdgcn_global_load_lds((const __attribute__((address_space(1))) void*)(agp0 + ko),
                                         (__attribute__((address_space(3))) void*)la, 16, 0, 0);
        __builtin_amdgcn_global_load_lds((const __attribute__((address_space(1))) void*)(agp1 + ko),
                                         (__attribute__((address_space(3))) void*)(la + 16 * 32), 16, 0, 0);
        __builtin_amdgcn_global_load_lds((const __attribute__((address_space(1))) void*)(bgp0 + ko),
                                         (__attribute__((address_space(3))) void*)lb, 16, 0, 0);
        __builtin_amdgcn_global_load_lds((const __attribute__((address_space(1))) void*)(bgp1 + ko),
                                         (__attribute__((address_space(3))) void*)(lb + 16 * 32), 16, 0, 0);
    };

    int nk = Keff / 32;
    stage(0, 0);
    __syncthreads();
    int buf = 0;
    for (int kt = 0; kt < nk; ++kt) {
        if (kt + 1 < nk) stage(buf ^ 1, kt + 1);
        bf16x8 af[4], bfr[4];
        #pragma unroll
        for (int i = 0; i < 4; ++i) {
            af[i] = *reinterpret_cast<const bf16x8*>(&As[buf][(wm + i * 16 + li) * 32 + lg * 8]);
            bfr[i] = *reinterpret_cast<const bf16x8*>(&Bs[buf][(wn + i * 16 + li) * 32 + lg * 8]);
        }
        #pragma unroll
        for (int mi = 0; mi < 4; ++mi)
            #pragma unroll
            for (int ni = 0; ni < 4; ++ni)
                acc[mi][ni] = __builtin_amdgcn_mfma_f32_16x16x32_bf16(af[mi], bfr[ni], acc[mi][ni], 0, 0, 0);
        __syncthreads();
        buf ^= 1;
    }

    #pragma unroll
    for (int mi = 0; mi < 4; ++mi) {
        #pragma unroll
        for (int r = 0; r < 4; ++r) {
            int row = m0 + wm + mi * 16 + lg * 4 + r;
            #pragma unroll
            for (int ni = 0; ni < 4; ++ni) {
                int col = n0 + wn + ni * 16 + li;
                if (EPI == EPI_RESK) {
                    float v = acc[mi][ni][r] + (split == 0 ? bias[col] : 0.f);
                    atomicAdd(&outf[(size_t)row * N + col], v);
                } else {
                    float v = acc[mi][ni][r] + bias[col];
                    if (EPI == EPI_GELU) outh[(size_t)row * N + col] = f2bf(gelu_f(v));
                    if (EPI == EPI_RES)  outf[(size_t)row * N + col] = res[(size_t)row * N + col] + v;
                    if (EPI == EPI_QKV) {
                        int which = col / 768;
                        int c2 = col - which * 768;
                        outh[(size_t)which * (8192 * 768) + (size_t)row * 768 + c2] = f2bf(v);
                    }
                }
            }
        }
    }
}

// ---------------- flash attention v8: ones-MFMA ell + defer-max + setprio --
// grid (8, 12, 8); 4 waves; wave w owns q-rows [qt*128 + w*32, +32) as 2 frags
__launch_bounds__(256, 3)
__global__ void flash_attn(const ushort* __restrict__ q, const ushort* __restrict__ k,
                           const ushort* __restrict__ v, ushort* __restrict__ o) {
    int flat = blockIdx.x + 8 * (blockIdx.y + 12 * blockIdx.z);
    flat = (flat & 7) * 96 + (flat >> 3);
    int qt = flat & 7;
    int rem = flat >> 3;
    int h = rem % 12;
    int b = rem / 12;

    int t = threadIdx.x, w = t >> 6, l = t & 63;
    int lg = l >> 4, li = l & 15;

    __shared__ __align__(16) ushort Vt[2][64][72];  // V^T tile, stride 144B
    __shared__ __align__(16) ushort P[4][32][72];   // per-wave P[q][kv]

    const size_t hoff = (size_t)h * 64;
    const size_t bbase = (size_t)b * 1024 * 768;

    bf16x8 qf[2][2];
    #pragma unroll
    for (int f = 0; f < 2; ++f) {
        int qrow = qt * 128 + w * 32 + f * 16 + li;
        const ushort* qp = &q[bbase + (size_t)qrow * 768 + hoff];
        qf[f][0] = *reinterpret_cast<const bf16x8*>(qp + lg * 8);
        qf[f][1] = *reinterpret_cast<const bf16x8*>(qp + 32 + lg * 8);
    }

    bf16x8 onesf;
    #pragma unroll
    for (int i = 0; i < 8; ++i) onesf[i] = (__bf16)1.0f;

    float m_[2][4];
    f32x4 oacc[2][4];
    f32x4 oell[2];
    #pragma unroll
    for (int f = 0; f < 2; ++f) {
        #pragma unroll
        for (int r = 0; r < 4; ++r) m_[f][r] = -1e30f;
        oell[f] = f32x4{0.f, 0.f, 0.f, 0.f};
        #pragma unroll
        for (int n = 0; n < 4; ++n) oacc[f][n] = f32x4{0.f, 0.f, 0.f, 0.f};
    }

    int vrow = t & 63;
    int vc = t >> 6;
    const ushort* vbase = &v[bbase + hoff];

    ushort8 vv0 = *reinterpret_cast<const ushort8*>(&vbase[(size_t)vrow * 768 + vc * 8]);
    ushort8 vv1 = *reinterpret_cast<const ushort8*>(&vbase[(size_t)vrow * 768 + (vc + 4) * 8]);

    for (int jt = 0; jt < 16; ++jt) {
        int j0 = jt * 64, buf = jt & 1;
        #pragma unroll
        for (int i = 0; i < 8; ++i) Vt[buf][vc * 8 + i][vrow] = vv0[i];
        #pragma unroll
        for (int i = 0; i < 8; ++i) Vt[buf][(vc + 4) * 8 + i][vrow] = vv1[i];
        if (jt < 15) {
            vv0 = *reinterpret_cast<const ushort8*>(&vbase[(size_t)(j0 + 64 + vrow) * 768 + vc * 8]);
            vv1 = *reinterpret_cast<const ushort8*>(&vbase[(size_t)(j0 + 64 + vrow) * 768 + (vc + 4) * 8]);
        }
        bf16x8 kf0[4], kf1[4];
        #pragma unroll
        for (int jj = 0; jj < 4; ++jj) {
            const ushort* kp = &k[bbase + (size_t)(j0 + jj * 16 + li) * 768 + hoff];
            kf0[jj] = *reinterpret_cast<const bf16x8*>(kp + lg * 8);
            kf1[jj] = *reinterpret_cast<const bf16x8*>(kp + 32 + lg * 8);
        }
        f32x4 s[2][4];
        __builtin_amdgcn_s_setprio(1);
        #pragma unroll
        for (int jj = 0; jj < 4; ++jj)
            #pragma unroll
            for (int f = 0; f < 2; ++f) {
                f32x4 a = {0.f, 0.f, 0.f, 0.f};
                a = __builtin_amdgcn_mfma_f32_16x16x32_bf16(qf[f][0], kf0[jj], a, 0, 0, 0);
                a = __builtin_amdgcn_mfma_f32_16x16x32_bf16(qf[f][1], kf1[jj], a, 0, 0, 0);
                s[f][jj] = a * 0.125f;
            }
        __builtin_amdgcn_s_setprio(0);
        #pragma unroll
        for (int f = 0; f < 2; ++f) {
            float mt[4];
            #pragma unroll
            for (int r = 0; r < 4; ++r)
                mt[r] = fmaxf(fmaxf(s[f][0][r], s[f][1][r]), fmaxf(s[f][2][r], s[f][3][r]));
            #pragma unroll
            for (int r = 0; r < 4; ++r) {
                mt[r] = fmaxf(mt[r], __shfl_xor(mt[r], 1));
                mt[r] = fmaxf(mt[r], __shfl_xor(mt[r], 2));
                mt[r] = fmaxf(mt[r], __shfl_xor(mt[r], 4));
                mt[r] = fmaxf(mt[r], __shfl_xor(mt[r], 8));
            }
            bool need = (mt[0] > m_[f][0] + 8.f) | (mt[1] > m_[f][1] + 8.f) |
                        (mt[2] > m_[f][2] + 8.f) | (mt[3] > m_[f][3] + 8.f);
            if (__any(need)) {
                #pragma unroll
                for (int r = 0; r < 4; ++r) {
                    float mn = fmaxf(m_[f][r], mt[r]);
                    float al = __expf(m_[f][r] - mn);
                    m_[f][r] = mn;
                    #pragma unroll
                    for (int n = 0; n < 4; ++n) oacc[f][n][r] *= al;
                    oell[f][r] *= al;
                }
            }
            #pragma unroll
            for (int jj = 0; jj < 4; ++jj)
                #pragma unroll
                for (int r = 0; r < 4; ++r)
                    P[w][f * 16 + lg * 4 + r][jj * 16 + li] = f2bf(__expf(s[f][jj][r] - m_[f][r]));
        }
        __syncthreads();
        bf16x8 pf[2][2];
        #pragma unroll
        for (int f = 0; f < 2; ++f) {
            pf[f][0] = *reinterpret_cast<const bf16x8*>(&P[w][f * 16 + li][lg * 8]);
            pf[f][1] = *reinterpret_cast<const bf16x8*>(&P[w][f * 16 + li][32 + lg * 8]);
        }
        __builtin_amdgcn_s_setprio(1);
        #pragma unroll
        for (int f = 0; f < 2; ++f) {
            oell[f] = __builtin_amdgcn_mfma_f32_16x16x32_bf16(pf[f][0], onesf, oell[f], 0, 0, 0);
            oell[f] = __builtin_amdgcn_mfma_f32_16x16x32_bf16(pf[f][1], onesf, oell[f], 0, 0, 0);
        }
        #pragma unroll
        for (int n = 0; n < 4; ++n) {
            bf16x8 vf0 = *reinterpret_cast<const bf16x8*>(&Vt[buf][n * 16 + li][lg * 8]);
            bf16x8 vf1 = *reinterpret_cast<const bf16x8*>(&Vt[buf][n * 16 + li][32 + lg * 8]);
            #pragma unroll
            for (int f = 0; f < 2; ++f) {
                oacc[f][n] = __builtin_amdgcn_mfma_f32_16x16x32_bf16(pf[f][0], vf0, oacc[f][n], 0, 0, 0);
                oacc[f][n] = __builtin_amdgcn_mfma_f32_16x16x32_bf16(pf[f][1], vf1, oacc[f][n], 0, 0, 0);
            }
        }
        __builtin_amdgcn_s_setprio(0);
    }
    #pragma unroll
    for (int f = 0; f < 2; ++f)
        #pragma unroll
        for (int n = 0; n < 4; ++n)
            #pragma unroll
            for (int r = 0; r < 4; ++r) {
                int row = qt * 128 + w * 32 + f * 16 + lg * 4 + r;
                o[bbase + (size_t)row * 768 + hoff + n * 16 + li] = f2bf(oacc[f][n][r] / oell[f][r]);
            }
}

// ---------------------------------------------------------------------------
extern "C" void kernel_launch(void* const* d_in, const int* in_sizes, int n_in,
                              void* d_out, int out_size, void* d_ws, size_t ws_size,
                              hipStream_t stream) {
    const float* x = (const float*)d_in[0];
    const float* dp_w = (const float*)d_in[1];
    const float* dp_b = (const float*)d_in[2];
    const float* se_w1 = (const float*)d_in[3];
    const float* se_b1 = (const float*)d_in[4];
    const float* se_w2 = (const float*)d_in[5];
    const float* se_b2 = (const float*)d_in[6];
    const float* wq = (const float*)d_in[7];  const float* bq = (const float*)d_in[8];
    const float* wk = (const float*)d_in[9];  const float* bk = (const float*)d_in[10];
    const float* wv = (const float*)d_in[11]; const float* bv = (const float*)d_in[12];
    const float* wo = (const float*)d_in[13]; const float* bo = (const float*)d_in[14];
    const float* gw1 = (const float*)d_in[15]; const float* gb1 = (const float*)d_in[16];
    const float* gw2 = (const float*)d_in[17]; const float* gb2 = (const float*)d_in[18];
    const float* n1g = (const float*)d_in[19]; const float* n1b = (const float*)d_in[20];
    const float* n2g = (const float*)d_in[21]; const float* n2b = (const float*)d_in[22];
    float* out = (float*)d_out;

    constexpr size_t SZ_ACT = (size_t)8192 * 768 * 2;  // bytes per bf16 activation
    char* W = (char*)d_ws;
    ushort* xb = (ushort*)(W);                  // bf16 x; later reused as xn
    ushort* q_ = (ushort*)(W + SZ_ACT);
    ushort* k_ = (ushort*)(W + 2 * SZ_ACT);
    ushort* v_ = (ushort*)(W + 3 * SZ_ACT);
    ushort* o_ = (ushort*)(W + 4 * SZ_ACT);
    ushort* hsp = q_;
    ushort* hff = q_;
    ushort* wqt = (ushort*)(W + 5 * SZ_ACT);    // contiguous qkv weight [2304][768]
    ushort* wkt = wqt + (size_t)768 * 768;
    ushort* wvt = wkt + (size_t)768 * 768;
    ushort* wot = wvt + (size_t)768 * 768;
    ushort* sw2t = wot + (size_t)768 * 768;
    ushort* g1t = sw2t + (size_t)768 * 768;
    ushort* g2t = g1t + (size_t)768 * 3072;
    float* sqv = (float*)(g2t + (size_t)3072 * 768);
    float* meanv = sqv + 8192;
    float* Avec = meanv + 8192;
    float* Cvec = Avec + 768;
    float* bqkv = Cvec + 768;                   // concat bias [2304]

    dim3 tb(32, 8);
    transpose_to_bf16<<<dim3(24, 24), tb, 0, stream>>>(se_w2, sw2t, 768, 768);
    transpose_to_bf16<<<dim3(24, 24), tb, 0, stream>>>(wq, wqt, 768, 768);
    transpose_to_bf16<<<dim3(24, 24), tb, 0, stream>>>(wk, wkt, 768, 768);
    transpose_to_bf16<<<dim3(24, 24), tb, 0, stream>>>(wv, wvt, 768, 768);
    transpose_to_bf16<<<dim3(24, 24), tb, 0, stream>>>(wo, wot, 768, 768);
    transpose_to_bf16<<<dim3(24, 96), tb, 0, stream>>>(gw1, g1t, 768, 3072);
    transpose_to_bf16<<<dim3(96, 24), tb, 0, stream>>>(gw2, g2t, 3072, 768);
    hipMemcpyAsync(bqkv, bq, 768 * sizeof(float), hipMemcpyDeviceToDevice, stream);
    hipMemcpyAsync(bqkv + 768, bk, 768 * sizeof(float), hipMemcpyDeviceToDevice, stream);
    hipMemcpyAsync(bqkv + 1536, bv, 768 * sizeof(float), hipMemcpyDeviceToDevice, stream);

    rowstat<<<8192, 256, 0, stream>>>(x, xb, sqv);
    precomp_ac<<<3, 256, 0, stream>>>(dp_w, dp_b, se_w1, se_b1, Avec, Cvec);
    hipMemsetAsync(meanv, 0, 8192 * sizeof(float), stream);

    // Gram -> distance row-sums (batch-per-XCD, L2-resident)
    gemm_bt<EPI_GRAM, 128><<<dim3(8, 8, 8), 256, 0, stream>>>(xb, xb, 1024, 1024, 768,
                                                              nullptr, nullptr, nullptr, nullptr, sqv, meanv);
    hgen<<<8192, 256, 0, stream>>>(meanv, Avec, Cvec, hsp);
    // x = x + h @ se_w2 + se_b2  -> d_out (fp32 residual stream)
    gemm4<EPI_RES><<<dim3(64, 6), 256, 0, stream>>>(hsp, sw2t, 8192, 768, 768,
                                                    se_b2, x, out, nullptr);
    // attention block
    lnorm<<<8192, 256, 0, stream>>>(out, n1g, n1b, xb);
    gemm4<EPI_QKV><<<dim3(64, 18), 256, 0, stream>>>(xb, wqt, 8192, 2304, 768,
                                                     bqkv, nullptr, nullptr, q_);
    flash_attn<<<dim3(8, 12, 8), 256, 0, stream>>>(q_, k_, v_, o_);
    gemm4<EPI_RES><<<dim3(64, 6), 256, 0, stream>>>(o_, wot, 8192, 768, 768,
                                                    bo, out, out, nullptr);
    // FFN block
    lnorm<<<8192, 256, 0, stream>>>(out, n2g, n2b, xb);
    gemm4<EPI_GELU><<<dim3(64, 24), 256, 0, stream>>>(xb, g1t, 8192, 3072, 768,
                                                      gb1, nullptr, nullptr, hff);
    // FFN2 split-K=2: atomicAdd partials onto out (already holds residual)
    gemm4<EPI_RESK><<<dim3(64, 6, 2), 256, 0, stream>>>(hff, g2t, 8192, 768, 3072,
                                                        gb2, nullptr, out, nullptr);
}

// Round 14
// 426.883 us; speedup vs baseline: 1.0071x; 1.0071x over previous
//
#include <hip/hip_runtime.h>
#include <hip/hip_bf16.h>

typedef unsigned short ushort;
typedef __attribute__((ext_vector_type(8))) __bf16 bf16x8;
typedef __attribute__((ext_vector_type(4))) float f32x4;
typedef __attribute__((ext_vector_type(8))) ushort ushort8;

__device__ inline ushort f2bf(float f) {
    union { float f; unsigned u; } a{f};
    unsigned r = a.u + 0x7FFFu + ((a.u >> 16) & 1u);
    return (ushort)(r >> 16);
}
__device__ inline float gelu_f(float x) {
    return 0.5f * x * (1.f + erff(x * 0.70710678118654752f));
}

// ---------------- transpose weight [K,N] fp32 -> [N,K] bf16 ----------------
__global__ void transpose_to_bf16(const float* __restrict__ Wm, ushort* __restrict__ Wt, int K, int N) {
    __shared__ float tile[32][33];
    int k0 = blockIdx.x * 32, n0 = blockIdx.y * 32;
    int tx = threadIdx.x, ty = threadIdx.y;
    #pragma unroll
    for (int r = ty; r < 32; r += 8) tile[r][tx] = Wm[(size_t)(k0 + r) * N + n0 + tx];
    __syncthreads();
    #pragma unroll
    for (int r = ty; r < 32; r += 8) Wt[(size_t)(n0 + r) * K + k0 + tx] = f2bf(tile[tx][r]);
}

// ---------------- row stats: xb (bf16 copy) + sq (sum of squares) ----------
__global__ void rowstat(const float* __restrict__ x, ushort* __restrict__ xb, float* __restrict__ sq) {
    int row = blockIdx.x;
    const float* xr = x + (size_t)row * 768;
    ushort* xbr = xb + (size_t)row * 768;
    int t = threadIdx.x;
    float s = 0.f;
    #pragma unroll
    for (int i = 0; i < 3; ++i) {
        float vv = xr[t + i * 256];
        xbr[t + i * 256] = f2bf(vv);
        s += vv * vv;
    }
    #pragma unroll
    for (int off = 1; off < 64; off <<= 1) s += __shfl_xor(s, off);
    __shared__ float wsum[4];
    if ((t & 63) == 0) wsum[t >> 6] = s;
    __syncthreads();
    if (t == 0) sq[row] = wsum[0] + wsum[1] + wsum[2] + wsum[3];
}

// ---------------- fold dp/se_w1 into rank-1 vectors ------------------------
__global__ void precomp_ac(const float* __restrict__ dp_w, const float* __restrict__ dp_b,
                           const float* __restrict__ se_w1, const float* __restrict__ se_b1,
                           float* __restrict__ Avec, float* __restrict__ Cvec) {
    int o = blockIdx.x * 256 + threadIdx.x;  // grid 3 -> 768
    float a = 0.f, c = 0.f;
    for (int i = 0; i < 192; ++i) {
        float w = se_w1[(size_t)i * 768 + o];
        a += dp_w[i] * w;
        c += dp_b[i] * w;
    }
    Avec[o] = a;
    Cvec[o] = c + se_b1[o];
}

// ---------------- spatial h generation (rank-1 + gelu) ---------------------
__global__ void hgen(const float* __restrict__ mean_acc, const float* __restrict__ Avec,
                     const float* __restrict__ Cvec, ushort* __restrict__ h) {
    int row = blockIdx.x;
    float md = mean_acc[row] * (1.f / 1024.f);
    int t = threadIdx.x;
    #pragma unroll
    for (int i = 0; i < 3; ++i) {
        int o = t + i * 256;
        h[(size_t)row * 768 + o] = f2bf(gelu_f(md * Avec[o] + Cvec[o]));
    }
}

// ---------------- layernorm fp32 -> bf16 -----------------------------------
__global__ void lnorm(const float* __restrict__ xin, const float* __restrict__ g,
                      const float* __restrict__ b, ushort* __restrict__ xn) {
    int row = blockIdx.x;
    const float* xr = xin + (size_t)row * 768;
    int t = threadIdx.x;
    float v[3];
    float s = 0.f, s2 = 0.f;
    #pragma unroll
    for (int i = 0; i < 3; ++i) {
        v[i] = xr[t + i * 256];
        s += v[i];
        s2 += v[i] * v[i];
    }
    #pragma unroll
    for (int off = 1; off < 64; off <<= 1) { s += __shfl_xor(s, off); s2 += __shfl_xor(s2, off); }
    __shared__ float a0[4], a1[4];
    if ((t & 63) == 0) { a0[t >> 6] = s; a1[t >> 6] = s2; }
    __syncthreads();
    s = a0[0] + a0[1] + a0[2] + a0[3];
    s2 = a1[0] + a1[1] + a1[2] + a1[3];
    float mu = s * (1.f / 768.f);
    float var = s2 * (1.f / 768.f) - mu * mu;
    float rs = rsqrtf(var + 1e-5f);
    #pragma unroll
    for (int i = 0; i < 3; ++i) {
        int o = t + i * 256;
        xn[(size_t)row * 768 + o] = f2bf((v[i] - mu) * rs * g[o] + b[o]);
    }
}

// ---------------- MFMA GEMM (2-phase, 128-tile): used for Gram only --------
#define BM 128
#define BK 32

enum { EPI_BF16 = 0, EPI_GELU = 1, EPI_RES = 2, EPI_GRAM = 3, EPI_QKV = 4, EPI_RESK = 5 };

template <int EPI, int BNT>
__launch_bounds__(256, BNT == 64 ? 4 : 2)
__global__ void gemm_bt(const ushort* __restrict__ A, const ushort* __restrict__ Bt,
                        int M, int N, int K,
                        const float* __restrict__ bias,
                        const float* res, float* outf,
                        ushort* __restrict__ outh,
                        const float* __restrict__ sq, float* __restrict__ mean_acc) {
    __shared__ __align__(16) ushort As[2][BM * BK];
    __shared__ __align__(16) ushort Bs[2][BNT * BK];

    unsigned gx = gridDim.x, gy = gridDim.y;
    unsigned flat = blockIdx.x + gx * (blockIdx.y + gy * blockIdx.z);
    unsigned total = gx * gy * gridDim.z;
    unsigned chunk = total >> 3;
    flat = (flat & 7) * chunk + (flat >> 3);
    unsigned bx = flat % gx;
    unsigned rem = flat / gx;
    unsigned by = rem % gy;
    unsigned bz = rem / gy;

    int m0 = bx * BM;
    int n0 = by * BNT;
    if (EPI == EPI_GRAM) {
        A += (size_t)bz * 1024 * 768;
        Bt = A;
        sq += bz * 1024;
        mean_acc += bz * 1024;
    }
    int t = threadIdx.x, w = t >> 6, l = t & 63;
    int lg = l >> 4, li = l & 15;
    constexpr int MI = (BNT == 128) ? 4 : 2;
    int wm = (BNT == 128) ? (w >> 1) * 64 : w * 32;
    int wn = (BNT == 128) ? (w & 1) * 64 : 0;

    int srow = l >> 2, scol = (l & 3) * 8;
    const ushort* agp0 = A + (size_t)(m0 + (2 * w) * 16 + srow) * K + scol;
    const ushort* agp1 = A + (size_t)(m0 + (2 * w + 1) * 16 + srow) * K + scol;
    const ushort* bgp0;
    const ushort* bgp1 = nullptr;
    ushort* la0 = &As[0][(2 * w) * 16 * BK];
    ushort* lb0;
    if (BNT == 128) {
        bgp0 = Bt + (size_t)(n0 + (2 * w) * 16 + srow) * K + scol;
        bgp1 = Bt + (size_t)(n0 + (2 * w + 1) * 16 + srow) * K + scol;
        lb0 = &Bs[0][(2 * w) * 16 * BK];
    } else {
        bgp0 = Bt + (size_t)(n0 + w * 16 + srow) * K + scol;
        lb0 = &Bs[0][w * 16 * BK];
    }

    f32x4 acc[MI][4] = {};

    auto stage = [&](int buf, int kt) {
        size_t ko = (size_t)kt * BK;
        ushort* la = la0 + buf * (BM * BK);
        ushort* lb = lb0 + buf * (BNT * BK);
        __builtin_amdgcn_global_load_lds((const __attribute__((address_space(1))) void*)(agp0 + ko),
                                         (__attribute__((address_space(3))) void*)la, 16, 0, 0);
        __builtin_amdgcn_global_load_lds((const __attribute__((address_space(1))) void*)(agp1 + ko),
                                         (__attribute__((address_space(3))) void*)(la + 16 * BK), 16, 0, 0);
        __builtin_amdgcn_global_load_lds((const __attribute__((address_space(1))) void*)(bgp0 + ko),
                                         (__attribute__((address_space(3))) void*)lb, 16, 0, 0);
        if (BNT == 128)
            __builtin_amdgcn_global_load_lds((const __attribute__((address_space(1))) void*)(bgp1 + ko),
                                             (__attribute__((address_space(3))) void*)(lb + 16 * BK), 16, 0, 0);
    };

    int nk = K / BK;
    stage(0, 0);
    __syncthreads();
    int buf = 0;
    for (int kt = 0; kt < nk; ++kt) {
        if (kt + 1 < nk) stage(buf ^ 1, kt + 1);
        bf16x8 af[MI], bfr[4];
        #pragma unroll
        for (int i = 0; i < MI; ++i)
            af[i] = *reinterpret_cast<const bf16x8*>(&As[buf][(wm + i * 16 + li) * BK + lg * 8]);
        #pragma unroll
        for (int i = 0; i < 4; ++i)
            bfr[i] = *reinterpret_cast<const bf16x8*>(&Bs[buf][(wn + i * 16 + li) * BK + lg * 8]);
        #pragma unroll
        for (int mi = 0; mi < MI; ++mi)
            #pragma unroll
            for (int ni = 0; ni < 4; ++ni)
                acc[mi][ni] = __builtin_amdgcn_mfma_f32_16x16x32_bf16(af[mi], bfr[ni], acc[mi][ni], 0, 0, 0);
        __syncthreads();
        buf ^= 1;
    }

    #pragma unroll
    for (int mi = 0; mi < MI; ++mi) {
        #pragma unroll
        for (int r = 0; r < 4; ++r) {
            int row = m0 + wm + mi * 16 + lg * 4 + r;
            if (EPI == EPI_GRAM) {
                float si = sq[row];
                float s = 0.f;
                #pragma unroll
                for (int ni = 0; ni < 4; ++ni) {
                    int col = n0 + wn + ni * 16 + li;
                    float d2 = si + sq[col] - 2.f * acc[mi][ni][r];
                    s += sqrtf(fmaxf(d2, 0.f));
                }
                s += __shfl_xor(s, 1); s += __shfl_xor(s, 2);
                s += __shfl_xor(s, 4); s += __shfl_xor(s, 8);
                if (li == 0) atomicAdd(&mean_acc[row], s);
            } else {
                #pragma unroll
                for (int ni = 0; ni < 4; ++ni) {
                    int col = n0 + wn + ni * 16 + li;
                    float v = acc[mi][ni][r] + bias[col];
                    if (EPI == EPI_BF16) outh[(size_t)row * N + col] = f2bf(v);
                    if (EPI == EPI_GELU) outh[(size_t)row * N + col] = f2bf(gelu_f(v));
                    if (EPI == EPI_RES) outf[(size_t)row * N + col] = res[(size_t)row * N + col] + v;
                    if (EPI == EPI_QKV) {
                        int which = col / 768;
                        int c2 = col - which * 768;
                        outh[(size_t)which * (8192 * 768) + (size_t)row * 768 + c2] = f2bf(v);
                    }
                }
            }
        }
    }
}

// ---------------- gemm4p: 128x128, m-split XCD, 3 blocks/CU, PIPELINED -----
// 4 waves, BK=32, 3-slot LDS (48 KB). Loads staged 2 iters ahead; counted
// s_waitcnt vmcnt(4) (never 0 in steady state) + raw s_barrier -> load
// latency off the critical path. LDS XOR swizzle (both-sides): stage source
// col ^= ((l>>3)&3), read col ^= ((li>>1)&3) -> each 16-lane quarter spreads
// over all 8 bank groups (2 lanes/group = free).
// EPI_RESK: split-K=2 via gridDim.z=2, fp32 atomicAdd onto outf (holds
// residual); bias added by split 0 only.
template <int EPI>
__launch_bounds__(256, 3)
__global__ void gemm4(const ushort* __restrict__ A, const ushort* __restrict__ Bt,
                      int M, int N, int K,
                      const float* __restrict__ bias,
                      const float* res, float* outf, ushort* __restrict__ outh) {
    __shared__ __align__(16) ushort As[3][128 * 32];
    __shared__ __align__(16) ushort Bs[3][128 * 32];

    // m-split: xcd owns gx/8 m-tiles x all (n, split); m fastest -> A L2-resident
    unsigned gx = gridDim.x, gy = gridDim.y;
    unsigned orig = blockIdx.x + gx * (blockIdx.y + gy * blockIdx.z);
    unsigned xcd = orig & 7;
    unsigned q = orig >> 3;
    unsigned mpg = gx >> 3;
    unsigned mloc = q % mpg;
    unsigned rest = q / mpg;
    unsigned n = rest % gy;
    unsigned split = rest / gy;              // 0 unless gridDim.z == 2
    int m0 = (xcd * mpg + mloc) * 128;
    int n0 = n * 128;
    int Keff = (EPI == EPI_RESK) ? (K >> 1) : K;
    int kbase = (EPI == EPI_RESK) ? (int)split * Keff : 0;

    int t = threadIdx.x, w = t >> 6, l = t & 63;
    int lg = l >> 4, li = l & 15;
    int wm = (w >> 1) * 64, wn = (w & 1) * 64;

    // staging: swizzled source column so linear LDS dest holds swizzled data
    int srow = l >> 2;
    int scol = ((l & 3) ^ ((l >> 3) & 3)) * 8;
    const ushort* agp0 = A + (size_t)(m0 + (2 * w) * 16 + srow) * K + kbase + scol;
    const ushort* agp1 = A + (size_t)(m0 + (2 * w + 1) * 16 + srow) * K + kbase + scol;
    const ushort* bgp0 = Bt + (size_t)(n0 + (2 * w) * 16 + srow) * K + kbase + scol;
    const ushort* bgp1 = Bt + (size_t)(n0 + (2 * w + 1) * 16 + srow) * K + kbase + scol;

    f32x4 acc[4][4] = {};

    auto stage = [&](int buf, int kt) {
        size_t ko = (size_t)kt * 32;
        ushort* la = &As[buf][(2 * w) * 16 * 32];
        ushort* lb = &Bs[buf][(2 * w) * 16 * 32];
        __builtin_amdgcn_global_load_lds((const __attribute__((address_space(1))) void*)(agp0 + ko),
                                         (__attribute__((address_space(3))) void*)la, 16, 0, 0);
        __builtin_amdgcn_global_load_lds((const __attribute__((address_space(1))) void*)(agp1 + ko),
                                         (__attribute__((address_space(3))) void*)(la + 16 * 32), 16, 0, 0);
        __builtin_amdgcn_global_load_lds((const __attribute__((address_space(1))) void*)(bgp0 + ko),
                                         (__attribute__((address_space(3))) void*)lb, 16, 0, 0);
        __builtin_amdgcn_global_load_lds((const __attribute__((address_space(1))) void*)(bgp1 + ko),
                                         (__attribute__((address_space(3))) void*)(lb + 16 * 32), 16, 0, 0);
    };

    int nk = Keff / 32;
    stage(0, 0);
    stage(1, 1);
    // per wave: 4 loads per stage; steady state 8 in flight, wait to 4.
    int rdsw = (lg ^ ((li >> 1) & 3)) * 8;   // swizzled read column
    for (int kt = 0; kt < nk; ++kt) {
        int buf = kt % 3;
        if (kt + 1 < nk) asm volatile("s_waitcnt vmcnt(4)" ::: "memory");
        else             asm volatile("s_waitcnt vmcnt(0)" ::: "memory");
        asm volatile("s_barrier" ::: "memory");   // tile kt landed in all waves
        __builtin_amdgcn_sched_barrier(0);
        bf16x8 af[4], bfr[4];
        #pragma unroll
        for (int i = 0; i < 4; ++i) {
            af[i] = *reinterpret_cast<const bf16x8*>(&As[buf][(wm + i * 16 + li) * 32 + rdsw]);
            bfr[i] = *reinterpret_cast<const bf16x8*>(&Bs[buf][(wn + i * 16 + li) * 32 + rdsw]);
        }
        __builtin_amdgcn_s_setprio(1);
        #pragma unroll
        for (int mi = 0; mi < 4; ++mi)
            #pragma unroll
            for (int ni = 0; ni < 4; ++ni)
                acc[mi][ni] = __builtin_amdgcn_mfma_f32_16x16x32_bf16(af[mi], bfr[ni], acc[mi][ni], 0, 0, 0);
        __builtin_amdgcn_s_setprio(0);
        asm volatile("s_barrier" ::: "memory");   // all waves done reading buf
        __builtin_amdgcn_sched_barrier(0);
        if (kt + 2 < nk) stage((kt + 2) % 3, kt + 2);
    }

    #pragma unroll
    for (int mi = 0; mi < 4; ++mi) {
        #pragma unroll
        for (int r = 0; r < 4; ++r) {
            int row = m0 + wm + mi * 16 + lg * 4 + r;
            #pragma unroll
            for (int ni = 0; ni < 4; ++ni) {
                int col = n0 + wn + ni * 16 + li;
                if (EPI == EPI_RESK) {
                    float v = acc[mi][ni][r] + (split == 0 ? bias[col] : 0.f);
                    atomicAdd(&outf[(size_t)row * N + col], v);
                } else {
                    float v = acc[mi][ni][r] + bias[col];
                    if (EPI == EPI_GELU) outh[(size_t)row * N + col] = f2bf(gelu_f(v));
                    if (EPI == EPI_RES)  outf[(size_t)row * N + col] = res[(size_t)row * N + col] + v;
                    if (EPI == EPI_QKV) {
                        int which = col / 768;
                        int c2 = col - which * 768;
                        outh[(size_t)which * (8192 * 768) + (size_t)row * 768 + c2] = f2bf(v);
                    }
                }
            }
        }
    }
}

// ---------------- flash attention v8: ones-MFMA ell + defer-max + setprio --
// grid (8, 12, 8); 4 waves; wave w owns q-rows [qt*128 + w*32, +32) as 2 frags
__launch_bounds__(256, 3)
__global__ void flash_attn(const ushort* __restrict__ q, const ushort* __restrict__ k,
                           const ushort* __restrict__ v, ushort* __restrict__ o) {
    int flat = blockIdx.x + 8 * (blockIdx.y + 12 * blockIdx.z);
    flat = (flat & 7) * 96 + (flat >> 3);
    int qt = flat & 7;
    int rem = flat >> 3;
    int h = rem % 12;
    int b = rem / 12;

    int t = threadIdx.x, w = t >> 6, l = t & 63;
    int lg = l >> 4, li = l & 15;

    __shared__ __align__(16) ushort Vt[2][64][72];  // V^T tile, stride 144B
    __shared__ __align__(16) ushort P[4][32][72];   // per-wave P[q][kv]

    const size_t hoff = (size_t)h * 64;
    const size_t bbase = (size_t)b * 1024 * 768;

    bf16x8 qf[2][2];
    #pragma unroll
    for (int f = 0; f < 2; ++f) {
        int qrow = qt * 128 + w * 32 + f * 16 + li;
        const ushort* qp = &q[bbase + (size_t)qrow * 768 + hoff];
        qf[f][0] = *reinterpret_cast<const bf16x8*>(qp + lg * 8);
        qf[f][1] = *reinterpret_cast<const bf16x8*>(qp + 32 + lg * 8);
    }

    bf16x8 onesf;
    #pragma unroll
    for (int i = 0; i < 8; ++i) onesf[i] = (__bf16)1.0f;

    float m_[2][4];
    f32x4 oacc[2][4];
    f32x4 oell[2];
    #pragma unroll
    for (int f = 0; f < 2; ++f) {
        #pragma unroll
        for (int r = 0; r < 4; ++r) m_[f][r] = -1e30f;
        oell[f] = f32x4{0.f, 0.f, 0.f, 0.f};
        #pragma unroll
        for (int n = 0; n < 4; ++n) oacc[f][n] = f32x4{0.f, 0.f, 0.f, 0.f};
    }

    int vrow = t & 63;
    int vc = t >> 6;
    const ushort* vbase = &v[bbase + hoff];

    ushort8 vv0 = *reinterpret_cast<const ushort8*>(&vbase[(size_t)vrow * 768 + vc * 8]);
    ushort8 vv1 = *reinterpret_cast<const ushort8*>(&vbase[(size_t)vrow * 768 + (vc + 4) * 8]);

    for (int jt = 0; jt < 16; ++jt) {
        int j0 = jt * 64, buf = jt & 1;
        #pragma unroll
        for (int i = 0; i < 8; ++i) Vt[buf][vc * 8 + i][vrow] = vv0[i];
        #pragma unroll
        for (int i = 0; i < 8; ++i) Vt[buf][(vc + 4) * 8 + i][vrow] = vv1[i];
        if (jt < 15) {
            vv0 = *reinterpret_cast<const ushort8*>(&vbase[(size_t)(j0 + 64 + vrow) * 768 + vc * 8]);
            vv1 = *reinterpret_cast<const ushort8*>(&vbase[(size_t)(j0 + 64 + vrow) * 768 + (vc + 4) * 8]);
        }
        bf16x8 kf0[4], kf1[4];
        #pragma unroll
        for (int jj = 0; jj < 4; ++jj) {
            const ushort* kp = &k[bbase + (size_t)(j0 + jj * 16 + li) * 768 + hoff];
            kf0[jj] = *reinterpret_cast<const bf16x8*>(kp + lg * 8);
            kf1[jj] = *reinterpret_cast<const bf16x8*>(kp + 32 + lg * 8);
        }
        f32x4 s[2][4];
        __builtin_amdgcn_s_setprio(1);
        #pragma unroll
        for (int jj = 0; jj < 4; ++jj)
            #pragma unroll
            for (int f = 0; f < 2; ++f) {
                f32x4 a = {0.f, 0.f, 0.f, 0.f};
                a = __builtin_amdgcn_mfma_f32_16x16x32_bf16(qf[f][0], kf0[jj], a, 0, 0, 0);
                a = __builtin_amdgcn_mfma_f32_16x16x32_bf16(qf[f][1], kf1[jj], a, 0, 0, 0);
                s[f][jj] = a * 0.125f;
            }
        __builtin_amdgcn_s_setprio(0);
        #pragma unroll
        for (int f = 0; f < 2; ++f) {
            float mt[4];
            #pragma unroll
            for (int r = 0; r < 4; ++r)
                mt[r] = fmaxf(fmaxf(s[f][0][r], s[f][1][r]), fmaxf(s[f][2][r], s[f][3][r]));
            #pragma unroll
            for (int r = 0; r < 4; ++r) {
                mt[r] = fmaxf(mt[r], __shfl_xor(mt[r], 1));
                mt[r] = fmaxf(mt[r], __shfl_xor(mt[r], 2));
                mt[r] = fmaxf(mt[r], __shfl_xor(mt[r], 4));
                mt[r] = fmaxf(mt[r], __shfl_xor(mt[r], 8));
            }
            bool need = (mt[0] > m_[f][0] + 8.f) | (mt[1] > m_[f][1] + 8.f) |
                        (mt[2] > m_[f][2] + 8.f) | (mt[3] > m_[f][3] + 8.f);
            if (__any(need)) {
                #pragma unroll
                for (int r = 0; r < 4; ++r) {
                    float mn = fmaxf(m_[f][r], mt[r]);
                    float al = __expf(m_[f][r] - mn);
                    m_[f][r] = mn;
                    #pragma unroll
                    for (int n = 0; n < 4; ++n) oacc[f][n][r] *= al;
                    oell[f][r] *= al;
                }
            }
            #pragma unroll
            for (int jj = 0; jj < 4; ++jj)
                #pragma unroll
                for (int r = 0; r < 4; ++r)
                    P[w][f * 16 + lg * 4 + r][jj * 16 + li] = f2bf(__expf(s[f][jj][r] - m_[f][r]));
        }
        __syncthreads();
        bf16x8 pf[2][2];
        #pragma unroll
        for (int f = 0; f < 2; ++f) {
            pf[f][0] = *reinterpret_cast<const bf16x8*>(&P[w][f * 16 + li][lg * 8]);
            pf[f][1] = *reinterpret_cast<const bf16x8*>(&P[w][f * 16 + li][32 + lg * 8]);
        }
        __builtin_amdgcn_s_setprio(1);
        #pragma unroll
        for (int f = 0; f < 2; ++f) {
            oell[f] = __builtin_amdgcn_mfma_f32_16x16x32_bf16(pf[f][0], onesf, oell[f], 0, 0, 0);
            oell[f] = __builtin_amdgcn_mfma_f32_16x16x32_bf16(pf[f][1], onesf, oell[f], 0, 0, 0);
        }
        #pragma unroll
        for (int n = 0; n < 4; ++n) {
            bf16x8 vf0 = *reinterpret_cast<const bf16x8*>(&Vt[buf][n * 16 + li][lg * 8]);
            bf16x8 vf1 = *reinterpret_cast<const bf16x8*>(&Vt[buf][n * 16 + li][32 + lg * 8]);
            #pragma unroll
            for (int f = 0; f < 2; ++f) {
                oacc[f][n] = __builtin_amdgcn_mfma_f32_16x16x32_bf16(pf[f][0], vf0, oacc[f][n], 0, 0, 0);
                oacc[f][n] = __builtin_amdgcn_mfma_f32_16x16x32_bf16(pf[f][1], vf1, oacc[f][n], 0, 0, 0);
            }
        }
        __builtin_amdgcn_s_setprio(0);
    }
    #pragma unroll
    for (int f = 0; f < 2; ++f)
        #pragma unroll
        for (int n = 0; n < 4; ++n)
            #pragma unroll
            for (int r = 0; r < 4; ++r) {
                int row = qt * 128 + w * 32 + f * 16 + lg * 4 + r;
                o[bbase + (size_t)row * 768 + hoff + n * 16 + li] = f2bf(oacc[f][n][r] / oell[f][r]);
            }
}

// ---------------------------------------------------------------------------
extern "C" void kernel_launch(void* const* d_in, const int* in_sizes, int n_in,
                              void* d_out, int out_size, void* d_ws, size_t ws_size,
                              hipStream_t stream) {
    const float* x = (const float*)d_in[0];
    const float* dp_w = (const float*)d_in[1];
    const float* dp_b = (const float*)d_in[2];
    const float* se_w1 = (const float*)d_in[3];
    const float* se_b1 = (const float*)d_in[4];
    const float* se_w2 = (const float*)d_in[5];
    const float* se_b2 = (const float*)d_in[6];
    const float* wq = (const float*)d_in[7];  const float* bq = (const float*)d_in[8];
    const float* wk = (const float*)d_in[9];  const float* bk = (const float*)d_in[10];
    const float* wv = (const float*)d_in[11]; const float* bv = (const float*)d_in[12];
    const float* wo = (const float*)d_in[13]; const float* bo = (const float*)d_in[14];
    const float* gw1 = (const float*)d_in[15]; const float* gb1 = (const float*)d_in[16];
    const float* gw2 = (const float*)d_in[17]; const float* gb2 = (const float*)d_in[18];
    const float* n1g = (const float*)d_in[19]; const float* n1b = (const float*)d_in[20];
    const float* n2g = (const float*)d_in[21]; const float* n2b = (const float*)d_in[22];
    float* out = (float*)d_out;

    constexpr size_t SZ_ACT = (size_t)8192 * 768 * 2;  // bytes per bf16 activation
    char* W = (char*)d_ws;
    ushort* xb = (ushort*)(W);                  // bf16 x; later reused as xn
    ushort* q_ = (ushort*)(W + SZ_ACT);
    ushort* k_ = (ushort*)(W + 2 * SZ_ACT);
    ushort* v_ = (ushort*)(W + 3 * SZ_ACT);
    ushort* o_ = (ushort*)(W + 4 * SZ_ACT);
    ushort* hsp = q_;
    ushort* hff = q_;
    ushort* wqt = (ushort*)(W + 5 * SZ_ACT);    // contiguous qkv weight [2304][768]
    ushort* wkt = wqt + (size_t)768 * 768;
    ushort* wvt = wkt + (size_t)768 * 768;
    ushort* wot = wvt + (size_t)768 * 768;
    ushort* sw2t = wot + (size_t)768 * 768;
    ushort* g1t = sw2t + (size_t)768 * 768;
    ushort* g2t = g1t + (size_t)768 * 3072;
    float* sqv = (float*)(g2t + (size_t)3072 * 768);
    float* meanv = sqv + 8192;
    float* Avec = meanv + 8192;
    float* Cvec = Avec + 768;
    float* bqkv = Cvec + 768;                   // concat bias [2304]

    dim3 tb(32, 8);
    transpose_to_bf16<<<dim3(24, 24), tb, 0, stream>>>(se_w2, sw2t, 768, 768);
    transpose_to_bf16<<<dim3(24, 24), tb, 0, stream>>>(wq, wqt, 768, 768);
    transpose_to_bf16<<<dim3(24, 24), tb, 0, stream>>>(wk, wkt, 768, 768);
    transpose_to_bf16<<<dim3(24, 24), tb, 0, stream>>>(wv, wvt, 768, 768);
    transpose_to_bf16<<<dim3(24, 24), tb, 0, stream>>>(wo, wot, 768, 768);
    transpose_to_bf16<<<dim3(24, 96), tb, 0, stream>>>(gw1, g1t, 768, 3072);
    transpose_to_bf16<<<dim3(96, 24), tb, 0, stream>>>(gw2, g2t, 3072, 768);
    hipMemcpyAsync(bqkv, bq, 768 * sizeof(float), hipMemcpyDeviceToDevice, stream);
    hipMemcpyAsync(bqkv + 768, bk, 768 * sizeof(float), hipMemcpyDeviceToDevice, stream);
    hipMemcpyAsync(bqkv + 1536, bv, 768 * sizeof(float), hipMemcpyDeviceToDevice, stream);

    rowstat<<<8192, 256, 0, stream>>>(x, xb, sqv);
    precomp_ac<<<3, 256, 0, stream>>>(dp_w, dp_b, se_w1, se_b1, Avec, Cvec);
    hipMemsetAsync(meanv, 0, 8192 * sizeof(float), stream);

    // Gram -> distance row-sums (batch-per-XCD, L2-resident)
    gemm_bt<EPI_GRAM, 128><<<dim3(8, 8, 8), 256, 0, stream>>>(xb, xb, 1024, 1024, 768,
                                                              nullptr, nullptr, nullptr, nullptr, sqv, meanv);
    hgen<<<8192, 256, 0, stream>>>(meanv, Avec, Cvec, hsp);
    // x = x + h @ se_w2 + se_b2  -> d_out (fp32 residual stream)
    gemm4<EPI_RES><<<dim3(64, 6), 256, 0, stream>>>(hsp, sw2t, 8192, 768, 768,
                                                    se_b2, x, out, nullptr);
    // attention block
    lnorm<<<8192, 256, 0, stream>>>(out, n1g, n1b, xb);
    gemm4<EPI_QKV><<<dim3(64, 18), 256, 0, stream>>>(xb, wqt, 8192, 2304, 768,
                                                     bqkv, nullptr, nullptr, q_);
    flash_attn<<<dim3(8, 12, 8), 256, 0, stream>>>(q_, k_, v_, o_);
    gemm4<EPI_RES><<<dim3(64, 6), 256, 0, stream>>>(o_, wot, 8192, 768, 768,
                                                    bo, out, out, nullptr);
    // FFN block
    lnorm<<<8192, 256, 0, stream>>>(out, n2g, n2b, xb);
    gemm4<EPI_GELU><<<dim3(64, 24), 256, 0, stream>>>(xb, g1t, 8192, 3072, 768,
                                                      gb1, nullptr, nullptr, hff);
    // FFN2 split-K=2: atomicAdd partials onto out (already holds residual)
    gemm4<EPI_RESK><<<dim3(64, 6, 2), 256, 0, stream>>>(hff, g2t, 8192, 768, 3072,
                                                        gb2, nullptr, out, nullptr);
}

// Round 15
// 419.966 us; speedup vs baseline: 1.0237x; 1.0165x over previous
//
#include <hip/hip_runtime.h>
#include <hip/hip_bf16.h>

typedef unsigned short ushort;
typedef __attribute__((ext_vector_type(8))) __bf16 bf16x8;
typedef __attribute__((ext_vector_type(4))) float f32x4;
typedef __attribute__((ext_vector_type(8))) ushort ushort8;

__device__ inline ushort f2bf(float f) {
    union { float f; unsigned u; } a{f};
    unsigned r = a.u + 0x7FFFu + ((a.u >> 16) & 1u);
    return (ushort)(r >> 16);
}
__device__ inline float gelu_f(float x) {
    return 0.5f * x * (1.f + erff(x * 0.70710678118654752f));
}

// ---------------- transpose weight [K,N] fp32 -> [N,K] bf16 ----------------
__global__ void transpose_to_bf16(const float* __restrict__ Wm, ushort* __restrict__ Wt, int K, int N) {
    __shared__ float tile[32][33];
    int k0 = blockIdx.x * 32, n0 = blockIdx.y * 32;
    int tx = threadIdx.x, ty = threadIdx.y;
    #pragma unroll
    for (int r = ty; r < 32; r += 8) tile[r][tx] = Wm[(size_t)(k0 + r) * N + n0 + tx];
    __syncthreads();
    #pragma unroll
    for (int r = ty; r < 32; r += 8) Wt[(size_t)(n0 + r) * K + k0 + tx] = f2bf(tile[tx][r]);
}

// ---------------- row stats: xb (bf16 copy) + sq (sum of squares) ----------
__global__ void rowstat(const float* __restrict__ x, ushort* __restrict__ xb, float* __restrict__ sq) {
    int row = blockIdx.x;
    const float* xr = x + (size_t)row * 768;
    ushort* xbr = xb + (size_t)row * 768;
    int t = threadIdx.x;
    float s = 0.f;
    #pragma unroll
    for (int i = 0; i < 3; ++i) {
        float vv = xr[t + i * 256];
        xbr[t + i * 256] = f2bf(vv);
        s += vv * vv;
    }
    #pragma unroll
    for (int off = 1; off < 64; off <<= 1) s += __shfl_xor(s, off);
    __shared__ float wsum[4];
    if ((t & 63) == 0) wsum[t >> 6] = s;
    __syncthreads();
    if (t == 0) sq[row] = wsum[0] + wsum[1] + wsum[2] + wsum[3];
}

// ---------------- fold dp/se_w1 into rank-1 vectors ------------------------
__global__ void precomp_ac(const float* __restrict__ dp_w, const float* __restrict__ dp_b,
                           const float* __restrict__ se_w1, const float* __restrict__ se_b1,
                           float* __restrict__ Avec, float* __restrict__ Cvec) {
    int o = blockIdx.x * 256 + threadIdx.x;  // grid 3 -> 768
    float a = 0.f, c = 0.f;
    for (int i = 0; i < 192; ++i) {
        float w = se_w1[(size_t)i * 768 + o];
        a += dp_w[i] * w;
        c += dp_b[i] * w;
    }
    Avec[o] = a;
    Cvec[o] = c + se_b1[o];
}

// ---------------- spatial h generation (rank-1 + gelu) ---------------------
__global__ void hgen(const float* __restrict__ mean_acc, const float* __restrict__ Avec,
                     const float* __restrict__ Cvec, ushort* __restrict__ h) {
    int row = blockIdx.x;
    float md = mean_acc[row] * (1.f / 1024.f);
    int t = threadIdx.x;
    #pragma unroll
    for (int i = 0; i < 3; ++i) {
        int o = t + i * 256;
        h[(size_t)row * 768 + o] = f2bf(gelu_f(md * Avec[o] + Cvec[o]));
    }
}

// ---------------- layernorm fp32 -> bf16 -----------------------------------
__global__ void lnorm(const float* __restrict__ xin, const float* __restrict__ g,
                      const float* __restrict__ b, ushort* __restrict__ xn) {
    int row = blockIdx.x;
    const float* xr = xin + (size_t)row * 768;
    int t = threadIdx.x;
    float v[3];
    float s = 0.f, s2 = 0.f;
    #pragma unroll
    for (int i = 0; i < 3; ++i) {
        v[i] = xr[t + i * 256];
        s += v[i];
        s2 += v[i] * v[i];
    }
    #pragma unroll
    for (int off = 1; off < 64; off <<= 1) { s += __shfl_xor(s, off); s2 += __shfl_xor(s2, off); }
    __shared__ float a0[4], a1[4];
    if ((t & 63) == 0) { a0[t >> 6] = s; a1[t >> 6] = s2; }
    __syncthreads();
    s = a0[0] + a0[1] + a0[2] + a0[3];
    s2 = a1[0] + a1[1] + a1[2] + a1[3];
    float mu = s * (1.f / 768.f);
    float var = s2 * (1.f / 768.f) - mu * mu;
    float rs = rsqrtf(var + 1e-5f);
    #pragma unroll
    for (int i = 0; i < 3; ++i) {
        int o = t + i * 256;
        xn[(size_t)row * 768 + o] = f2bf((v[i] - mu) * rs * g[o] + b[o]);
    }
}

// ---------------- MFMA GEMM (2-phase, 128-tile): used for Gram only --------
#define BM 128
#define BK 32

enum { EPI_BF16 = 0, EPI_GELU = 1, EPI_RES = 2, EPI_GRAM = 3, EPI_QKV = 4, EPI_RESK = 5 };

template <int EPI, int BNT>
__launch_bounds__(256, BNT == 64 ? 4 : 2)
__global__ void gemm_bt(const ushort* __restrict__ A, const ushort* __restrict__ Bt,
                        int M, int N, int K,
                        const float* __restrict__ bias,
                        const float* res, float* outf,
                        ushort* __restrict__ outh,
                        const float* __restrict__ sq, float* __restrict__ mean_acc) {
    __shared__ __align__(16) ushort As[2][BM * BK];
    __shared__ __align__(16) ushort Bs[2][BNT * BK];

    unsigned gx = gridDim.x, gy = gridDim.y;
    unsigned flat = blockIdx.x + gx * (blockIdx.y + gy * blockIdx.z);
    unsigned total = gx * gy * gridDim.z;
    unsigned chunk = total >> 3;
    flat = (flat & 7) * chunk + (flat >> 3);
    unsigned bx = flat % gx;
    unsigned rem = flat / gx;
    unsigned by = rem % gy;
    unsigned bz = rem / gy;

    int m0 = bx * BM;
    int n0 = by * BNT;
    if (EPI == EPI_GRAM) {
        A += (size_t)bz * 1024 * 768;
        Bt = A;
        sq += bz * 1024;
        mean_acc += bz * 1024;
    }
    int t = threadIdx.x, w = t >> 6, l = t & 63;
    int lg = l >> 4, li = l & 15;
    constexpr int MI = (BNT == 128) ? 4 : 2;
    int wm = (BNT == 128) ? (w >> 1) * 64 : w * 32;
    int wn = (BNT == 128) ? (w & 1) * 64 : 0;

    int srow = l >> 2, scol = (l & 3) * 8;
    const ushort* agp0 = A + (size_t)(m0 + (2 * w) * 16 + srow) * K + scol;
    const ushort* agp1 = A + (size_t)(m0 + (2 * w + 1) * 16 + srow) * K + scol;
    const ushort* bgp0;
    const ushort* bgp1 = nullptr;
    ushort* la0 = &As[0][(2 * w) * 16 * BK];
    ushort* lb0;
    if (BNT == 128) {
        bgp0 = Bt + (size_t)(n0 + (2 * w) * 16 + srow) * K + scol;
        bgp1 = Bt + (size_t)(n0 + (2 * w + 1) * 16 + srow) * K + scol;
        lb0 = &Bs[0][(2 * w) * 16 * BK];
    } else {
        bgp0 = Bt + (size_t)(n0 + w * 16 + srow) * K + scol;
        lb0 = &Bs[0][w * 16 * BK];
    }

    f32x4 acc[MI][4] = {};

    auto stage = [&](int buf, int kt) {
        size_t ko = (size_t)kt * BK;
        ushort* la = la0 + buf * (BM * BK);
        ushort* lb = lb0 + buf * (BNT * BK);
        __builtin_amdgcn_global_load_lds((const __attribute__((address_space(1))) void*)(agp0 + ko),
                                         (__attribute__((address_space(3))) void*)la, 16, 0, 0);
        __builtin_amdgcn_global_load_lds((const __attribute__((address_space(1))) void*)(agp1 + ko),
                                         (__attribute__((address_space(3))) void*)(la + 16 * BK), 16, 0, 0);
        __builtin_amdgcn_global_load_lds((const __attribute__((address_space(1))) void*)(bgp0 + ko),
                                         (__attribute__((address_space(3))) void*)lb, 16, 0, 0);
        if (BNT == 128)
            __builtin_amdgcn_global_load_lds((const __attribute__((address_space(1))) void*)(bgp1 + ko),
                                             (__attribute__((address_space(3))) void*)(lb + 16 * BK), 16, 0, 0);
    };

    int nk = K / BK;
    stage(0, 0);
    __syncthreads();
    int buf = 0;
    for (int kt = 0; kt < nk; ++kt) {
        if (kt + 1 < nk) stage(buf ^ 1, kt + 1);
        bf16x8 af[MI], bfr[4];
        #pragma unroll
        for (int i = 0; i < MI; ++i)
            af[i] = *reinterpret_cast<const bf16x8*>(&As[buf][(wm + i * 16 + li) * BK + lg * 8]);
        #pragma unroll
        for (int i = 0; i < 4; ++i)
            bfr[i] = *reinterpret_cast<const bf16x8*>(&Bs[buf][(wn + i * 16 + li) * BK + lg * 8]);
        #pragma unroll
        for (int mi = 0; mi < MI; ++mi)
            #pragma unroll
            for (int ni = 0; ni < 4; ++ni)
                acc[mi][ni] = __builtin_amdgcn_mfma_f32_16x16x32_bf16(af[mi], bfr[ni], acc[mi][ni], 0, 0, 0);
        __syncthreads();
        buf ^= 1;
    }

    #pragma unroll
    for (int mi = 0; mi < MI; ++mi) {
        #pragma unroll
        for (int r = 0; r < 4; ++r) {
            int row = m0 + wm + mi * 16 + lg * 4 + r;
            if (EPI == EPI_GRAM) {
                float si = sq[row];
                float s = 0.f;
                #pragma unroll
                for (int ni = 0; ni < 4; ++ni) {
                    int col = n0 + wn + ni * 16 + li;
                    float d2 = si + sq[col] - 2.f * acc[mi][ni][r];
                    s += sqrtf(fmaxf(d2, 0.f));
                }
                s += __shfl_xor(s, 1); s += __shfl_xor(s, 2);
                s += __shfl_xor(s, 4); s += __shfl_xor(s, 8);
                if (li == 0) atomicAdd(&mean_acc[row], s);
            } else {
                #pragma unroll
                for (int ni = 0; ni < 4; ++ni) {
                    int col = n0 + wn + ni * 16 + li;
                    float v = acc[mi][ni][r] + bias[col];
                    if (EPI == EPI_BF16) outh[(size_t)row * N + col] = f2bf(v);
                    if (EPI == EPI_GELU) outh[(size_t)row * N + col] = f2bf(gelu_f(v));
                    if (EPI == EPI_RES) outf[(size_t)row * N + col] = res[(size_t)row * N + col] + v;
                    if (EPI == EPI_QKV) {
                        int which = col / 768;
                        int c2 = col - which * 768;
                        outh[(size_t)which * (8192 * 768) + (size_t)row * 768 + c2] = f2bf(v);
                    }
                }
            }
        }
    }
}

// ---------------- gemm4p: 128x128, m-split XCD, 3 blocks/CU, PIPELINED -----
// 4 waves, BK=32, 3-slot LDS ring (48 KB), staged 2 iters ahead, counted
// vmcnt(4). SINGLE barrier per K-step: with a 3-slot ring, slot (kt+2)%3
// overwritten at end of iter kt was last read at iter kt-1, and every wave
// finished those reads before passing barrier #1 of iter kt -> the trailing
// barrier is redundant (writer-after-reader already ordered). LDS XOR
// swizzle both-sides (conflicts measured 0). EPI_RESK: split-K=2, fp32
// atomicAdd onto outf (holds residual); bias added by split 0 only.
template <int EPI>
__launch_bounds__(256, 3)
__global__ void gemm4(const ushort* __restrict__ A, const ushort* __restrict__ Bt,
                      int M, int N, int K,
                      const float* __restrict__ bias,
                      const float* res, float* outf, ushort* __restrict__ outh) {
    __shared__ __align__(16) ushort As[3][128 * 32];
    __shared__ __align__(16) ushort Bs[3][128 * 32];

    // m-split: xcd owns gx/8 m-tiles x all (n, split); m fastest -> A L2-resident
    unsigned gx = gridDim.x, gy = gridDim.y;
    unsigned orig = blockIdx.x + gx * (blockIdx.y + gy * blockIdx.z);
    unsigned xcd = orig & 7;
    unsigned q = orig >> 3;
    unsigned mpg = gx >> 3;
    unsigned mloc = q % mpg;
    unsigned rest = q / mpg;
    unsigned n = rest % gy;
    unsigned split = rest / gy;              // 0 unless gridDim.z == 2
    int m0 = (xcd * mpg + mloc) * 128;
    int n0 = n * 128;
    int Keff = (EPI == EPI_RESK) ? (K >> 1) : K;
    int kbase = (EPI == EPI_RESK) ? (int)split * Keff : 0;

    int t = threadIdx.x, w = t >> 6, l = t & 63;
    int lg = l >> 4, li = l & 15;
    int wm = (w >> 1) * 64, wn = (w & 1) * 64;

    // staging: swizzled source column so linear LDS dest holds swizzled data
    int srow = l >> 2;
    int scol = ((l & 3) ^ ((l >> 3) & 3)) * 8;
    const ushort* agp0 = A + (size_t)(m0 + (2 * w) * 16 + srow) * K + kbase + scol;
    const ushort* agp1 = A + (size_t)(m0 + (2 * w + 1) * 16 + srow) * K + kbase + scol;
    const ushort* bgp0 = Bt + (size_t)(n0 + (2 * w) * 16 + srow) * K + kbase + scol;
    const ushort* bgp1 = Bt + (size_t)(n0 + (2 * w + 1) * 16 + srow) * K + kbase + scol;

    f32x4 acc[4][4] = {};

    auto stage = [&](int buf, int kt) {
        size_t ko = (size_t)kt * 32;
        ushort* la = &As[buf][(2 * w) * 16 * 32];
        ushort* lb = &Bs[buf][(2 * w) * 16 * 32];
        __builtin_amdgcn_global_load_lds((const __attribute__((address_space(1))) void*)(agp0 + ko),
                                         (__attribute__((address_space(3))) void*)la, 16, 0, 0);
        __builtin_amdgcn_global_load_lds((const __attribute__((address_space(1))) void*)(agp1 + ko),
                                         (__attribute__((address_space(3))) void*)(la + 16 * 32), 16, 0, 0);
        __builtin_amdgcn_global_load_lds((const __attribute__((address_space(1))) void*)(bgp0 + ko),
                                         (__attribute__((address_space(3))) void*)lb, 16, 0, 0);
        __builtin_amdgcn_global_load_lds((const __attribute__((address_space(1))) void*)(bgp1 + ko),
                                         (__attribute__((address_space(3))) void*)(lb + 16 * 32), 16, 0, 0);
    };

    int nk = Keff / 32;
    stage(0, 0);
    stage(1, 1);
    // per wave: 4 loads per stage; steady state 8 in flight, wait to 4.
    int rdsw = (lg ^ ((li >> 1) & 3)) * 8;   // swizzled read column
    for (int kt = 0; kt < nk; ++kt) {
        int buf = kt % 3;
        if (kt + 1 < nk) asm volatile("s_waitcnt vmcnt(4)" ::: "memory");
        else             asm volatile("s_waitcnt vmcnt(0)" ::: "memory");
        asm volatile("s_barrier" ::: "memory");   // tile kt landed in all waves
        __builtin_amdgcn_sched_barrier(0);
        bf16x8 af[4], bfr[4];
        #pragma unroll
        for (int i = 0; i < 4; ++i) {
            af[i] = *reinterpret_cast<const bf16x8*>(&As[buf][(wm + i * 16 + li) * 32 + rdsw]);
            bfr[i] = *reinterpret_cast<const bf16x8*>(&Bs[buf][(wn + i * 16 + li) * 32 + rdsw]);
        }
        __builtin_amdgcn_s_setprio(1);
        #pragma unroll
        for (int mi = 0; mi < 4; ++mi)
            #pragma unroll
            for (int ni = 0; ni < 4; ++ni)
                acc[mi][ni] = __builtin_amdgcn_mfma_f32_16x16x32_bf16(af[mi], bfr[ni], acc[mi][ni], 0, 0, 0);
        __builtin_amdgcn_s_setprio(0);
        // no trailing barrier: slot (kt+2)%3 == (kt-1)%3 was fully consumed
        // before this iteration's barrier (see header comment).
        if (kt + 2 < nk) stage((kt + 2) % 3, kt + 2);
    }

    #pragma unroll
    for (int mi = 0; mi < 4; ++mi) {
        #pragma unroll
        for (int r = 0; r < 4; ++r) {
            int row = m0 + wm + mi * 16 + lg * 4 + r;
            #pragma unroll
            for (int ni = 0; ni < 4; ++ni) {
                int col = n0 + wn + ni * 16 + li;
                if (EPI == EPI_RESK) {
                    float v = acc[mi][ni][r] + (split == 0 ? bias[col] : 0.f);
                    atomicAdd(&outf[(size_t)row * N + col], v);
                } else {
                    float v = acc[mi][ni][r] + bias[col];
                    if (EPI == EPI_GELU) outh[(size_t)row * N + col] = f2bf(gelu_f(v));
                    if (EPI == EPI_RES)  outf[(size_t)row * N + col] = res[(size_t)row * N + col] + v;
                    if (EPI == EPI_QKV) {
                        int which = col / 768;
                        int c2 = col - which * 768;
                        outh[(size_t)which * (8192 * 768) + (size_t)row * 768 + c2] = f2bf(v);
                    }
                }
            }
        }
    }
}

// ---------------- flash attention v8: ones-MFMA ell + defer-max + setprio --
// grid (8, 12, 8); 4 waves; wave w owns q-rows [qt*128 + w*32, +32) as 2 frags
__launch_bounds__(256, 3)
__global__ void flash_attn(const ushort* __restrict__ q, const ushort* __restrict__ k,
                           const ushort* __restrict__ v, ushort* __restrict__ o) {
    int flat = blockIdx.x + 8 * (blockIdx.y + 12 * blockIdx.z);
    flat = (flat & 7) * 96 + (flat >> 3);
    int qt = flat & 7;
    int rem = flat >> 3;
    int h = rem % 12;
    int b = rem / 12;

    int t = threadIdx.x, w = t >> 6, l = t & 63;
    int lg = l >> 4, li = l & 15;

    __shared__ __align__(16) ushort Vt[2][64][72];  // V^T tile, stride 144B
    __shared__ __align__(16) ushort P[4][32][72];   // per-wave P[q][kv]

    const size_t hoff = (size_t)h * 64;
    const size_t bbase = (size_t)b * 1024 * 768;

    bf16x8 qf[2][2];
    #pragma unroll
    for (int f = 0; f < 2; ++f) {
        int qrow = qt * 128 + w * 32 + f * 16 + li;
        const ushort* qp = &q[bbase + (size_t)qrow * 768 + hoff];
        qf[f][0] = *reinterpret_cast<const bf16x8*>(qp + lg * 8);
        qf[f][1] = *reinterpret_cast<const bf16x8*>(qp + 32 + lg * 8);
    }

    bf16x8 onesf;
    #pragma unroll
    for (int i = 0; i < 8; ++i) onesf[i] = (__bf16)1.0f;

    float m_[2][4];
    f32x4 oacc[2][4];
    f32x4 oell[2];
    #pragma unroll
    for (int f = 0; f < 2; ++f) {
        #pragma unroll
        for (int r = 0; r < 4; ++r) m_[f][r] = -1e30f;
        oell[f] = f32x4{0.f, 0.f, 0.f, 0.f};
        #pragma unroll
        for (int n = 0; n < 4; ++n) oacc[f][n] = f32x4{0.f, 0.f, 0.f, 0.f};
    }

    int vrow = t & 63;
    int vc = t >> 6;
    const ushort* vbase = &v[bbase + hoff];

    ushort8 vv0 = *reinterpret_cast<const ushort8*>(&vbase[(size_t)vrow * 768 + vc * 8]);
    ushort8 vv1 = *reinterpret_cast<const ushort8*>(&vbase[(size_t)vrow * 768 + (vc + 4) * 8]);

    for (int jt = 0; jt < 16; ++jt) {
        int j0 = jt * 64, buf = jt & 1;
        #pragma unroll
        for (int i = 0; i < 8; ++i) Vt[buf][vc * 8 + i][vrow] = vv0[i];
        #pragma unroll
        for (int i = 0; i < 8; ++i) Vt[buf][(vc + 4) * 8 + i][vrow] = vv1[i];
        if (jt < 15) {
            vv0 = *reinterpret_cast<const ushort8*>(&vbase[(size_t)(j0 + 64 + vrow) * 768 + vc * 8]);
            vv1 = *reinterpret_cast<const ushort8*>(&vbase[(size_t)(j0 + 64 + vrow) * 768 + (vc + 4) * 8]);
        }
        bf16x8 kf0[4], kf1[4];
        #pragma unroll
        for (int jj = 0; jj < 4; ++jj) {
            const ushort* kp = &k[bbase + (size_t)(j0 + jj * 16 + li) * 768 + hoff];
            kf0[jj] = *reinterpret_cast<const bf16x8*>(kp + lg * 8);
            kf1[jj] = *reinterpret_cast<const bf16x8*>(kp + 32 + lg * 8);
        }
        f32x4 s[2][4];
        __builtin_amdgcn_s_setprio(1);
        #pragma unroll
        for (int jj = 0; jj < 4; ++jj)
            #pragma unroll
            for (int f = 0; f < 2; ++f) {
                f32x4 a = {0.f, 0.f, 0.f, 0.f};
                a = __builtin_amdgcn_mfma_f32_16x16x32_bf16(qf[f][0], kf0[jj], a, 0, 0, 0);
                a = __builtin_amdgcn_mfma_f32_16x16x32_bf16(qf[f][1], kf1[jj], a, 0, 0, 0);
                s[f][jj] = a * 0.125f;
            }
        __builtin_amdgcn_s_setprio(0);
        #pragma unroll
        for (int f = 0; f < 2; ++f) {
            float mt[4];
            #pragma unroll
            for (int r = 0; r < 4; ++r)
                mt[r] = fmaxf(fmaxf(s[f][0][r], s[f][1][r]), fmaxf(s[f][2][r], s[f][3][r]));
            #pragma unroll
            for (int r = 0; r < 4; ++r) {
                mt[r] = fmaxf(mt[r], __shfl_xor(mt[r], 1));
                mt[r] = fmaxf(mt[r], __shfl_xor(mt[r], 2));
                mt[r] = fmaxf(mt[r], __shfl_xor(mt[r], 4));
                mt[r] = fmaxf(mt[r], __shfl_xor(mt[r], 8));
            }
            bool need = (mt[0] > m_[f][0] + 8.f) | (mt[1] > m_[f][1] + 8.f) |
                        (mt[2] > m_[f][2] + 8.f) | (mt[3] > m_[f][3] + 8.f);
            if (__any(need)) {
                #pragma unroll
                for (int r = 0; r < 4; ++r) {
                    float mn = fmaxf(m_[f][r], mt[r]);
                    float al = __expf(m_[f][r] - mn);
                    m_[f][r] = mn;
                    #pragma unroll
                    for (int n = 0; n < 4; ++n) oacc[f][n][r] *= al;
                    oell[f][r] *= al;
                }
            }
            #pragma unroll
            for (int jj = 0; jj < 4; ++jj)
                #pragma unroll
                for (int r = 0; r < 4; ++r)
                    P[w][f * 16 + lg * 4 + r][jj * 16 + li] = f2bf(__expf(s[f][jj][r] - m_[f][r]));
        }
        __syncthreads();
        bf16x8 pf[2][2];
        #pragma unroll
        for (int f = 0; f < 2; ++f) {
            pf[f][0] = *reinterpret_cast<const bf16x8*>(&P[w][f * 16 + li][lg * 8]);
            pf[f][1] = *reinterpret_cast<const bf16x8*>(&P[w][f * 16 + li][32 + lg * 8]);
        }
        __builtin_amdgcn_s_setprio(1);
        #pragma unroll
        for (int f = 0; f < 2; ++f) {
            oell[f] = __builtin_amdgcn_mfma_f32_16x16x32_bf16(pf[f][0], onesf, oell[f], 0, 0, 0);
            oell[f] = __builtin_amdgcn_mfma_f32_16x16x32_bf16(pf[f][1], onesf, oell[f], 0, 0, 0);
        }
        #pragma unroll
        for (int n = 0; n < 4; ++n) {
            bf16x8 vf0 = *reinterpret_cast<const bf16x8*>(&Vt[buf][n * 16 + li][lg * 8]);
            bf16x8 vf1 = *reinterpret_cast<const bf16x8*>(&Vt[buf][n * 16 + li][32 + lg * 8]);
            #pragma unroll
            for (int f = 0; f < 2; ++f) {
                oacc[f][n] = __builtin_amdgcn_mfma_f32_16x16x32_bf16(pf[f][0], vf0, oacc[f][n], 0, 0, 0);
                oacc[f][n] = __builtin_amdgcn_mfma_f32_16x16x32_bf16(pf[f][1], vf1, oacc[f][n], 0, 0, 0);
            }
        }
        __builtin_amdgcn_s_setprio(0);
    }
    #pragma unroll
    for (int f = 0; f < 2; ++f)
        #pragma unroll
        for (int n = 0; n < 4; ++n)
            #pragma unroll
            for (int r = 0; r < 4; ++r) {
                int row = qt * 128 + w * 32 + f * 16 + lg * 4 + r;
                o[bbase + (size_t)row * 768 + hoff + n * 16 + li] = f2bf(oacc[f][n][r] / oell[f][r]);
            }
}

// ---------------------------------------------------------------------------
extern "C" void kernel_launch(void* const* d_in, const int* in_sizes, int n_in,
                              void* d_out, int out_size, void* d_ws, size_t ws_size,
                              hipStream_t stream) {
    const float* x = (const float*)d_in[0];
    const float* dp_w = (const float*)d_in[1];
    const float* dp_b = (const float*)d_in[2];
    const float* se_w1 = (const float*)d_in[3];
    const float* se_b1 = (const float*)d_in[4];
    const float* se_w2 = (const float*)d_in[5];
    const float* se_b2 = (const float*)d_in[6];
    const float* wq = (const float*)d_in[7];  const float* bq = (const float*)d_in[8];
    const float* wk = (const float*)d_in[9];  const float* bk = (const float*)d_in[10];
    const float* wv = (const float*)d_in[11]; const float* bv = (const float*)d_in[12];
    const float* wo = (const float*)d_in[13]; const float* bo = (const float*)d_in[14];
    const float* gw1 = (const float*)d_in[15]; const float* gb1 = (const float*)d_in[16];
    const float* gw2 = (const float*)d_in[17]; const float* gb2 = (const float*)d_in[18];
    const float* n1g = (const float*)d_in[19]; const float* n1b = (const float*)d_in[20];
    const float* n2g = (const float*)d_in[21]; const float* n2b = (const float*)d_in[22];
    float* out = (float*)d_out;

    constexpr size_t SZ_ACT = (size_t)8192 * 768 * 2;  // bytes per bf16 activation
    char* W = (char*)d_ws;
    ushort* xb = (ushort*)(W);                  // bf16 x; later reused as xn
    ushort* q_ = (ushort*)(W + SZ_ACT);
    ushort* k_ = (ushort*)(W + 2 * SZ_ACT);
    ushort* v_ = (ushort*)(W + 3 * SZ_ACT);
    ushort* o_ = (ushort*)(W + 4 * SZ_ACT);
    ushort* hsp = q_;
    ushort* hff = q_;
    ushort* wqt = (ushort*)(W + 5 * SZ_ACT);    // contiguous qkv weight [2304][768]
    ushort* wkt = wqt + (size_t)768 * 768;
    ushort* wvt = wkt + (size_t)768 * 768;
    ushort* wot = wvt + (size_t)768 * 768;
    ushort* sw2t = wot + (size_t)768 * 768;
    ushort* g1t = sw2t + (size_t)768 * 768;
    ushort* g2t = g1t + (size_t)768 * 3072;
    float* sqv = (float*)(g2t + (size_t)3072 * 768);
    float* meanv = sqv + 8192;
    float* Avec = meanv + 8192;
    float* Cvec = Avec + 768;
    float* bqkv = Cvec + 768;                   // concat bias [2304]

    dim3 tb(32, 8);
    transpose_to_bf16<<<dim3(24, 24), tb, 0, stream>>>(se_w2, sw2t, 768, 768);
    transpose_to_bf16<<<dim3(24, 24), tb, 0, stream>>>(wq, wqt, 768, 768);
    transpose_to_bf16<<<dim3(24, 24), tb, 0, stream>>>(wk, wkt, 768, 768);
    transpose_to_bf16<<<dim3(24, 24), tb, 0, stream>>>(wv, wvt, 768, 768);
    transpose_to_bf16<<<dim3(24, 24), tb, 0, stream>>>(wo, wot, 768, 768);
    transpose_to_bf16<<<dim3(24, 96), tb, 0, stream>>>(gw1, g1t, 768, 3072);
    transpose_to_bf16<<<dim3(96, 24), tb, 0, stream>>>(gw2, g2t, 3072, 768);
    hipMemcpyAsync(bqkv, bq, 768 * sizeof(float), hipMemcpyDeviceToDevice, stream);
    hipMemcpyAsync(bqkv + 768, bk, 768 * sizeof(float), hipMemcpyDeviceToDevice, stream);
    hipMemcpyAsync(bqkv + 1536, bv, 768 * sizeof(float), hipMemcpyDeviceToDevice, stream);

    rowstat<<<8192, 256, 0, stream>>>(x, xb, sqv);
    precomp_ac<<<3, 256, 0, stream>>>(dp_w, dp_b, se_w1, se_b1, Avec, Cvec);
    hipMemsetAsync(meanv, 0, 8192 * sizeof(float), stream);

    // Gram -> distance row-sums (batch-per-XCD, L2-resident)
    gemm_bt<EPI_GRAM, 128><<<dim3(8, 8, 8), 256, 0, stream>>>(xb, xb, 1024, 1024, 768,
                                                              nullptr, nullptr, nullptr, nullptr, sqv, meanv);
    hgen<<<8192, 256, 0, stream>>>(meanv, Avec, Cvec, hsp);
    // x = x + h @ se_w2 + se_b2  -> d_out (fp32 residual stream)
    gemm4<EPI_RES><<<dim3(64, 6), 256, 0, stream>>>(hsp, sw2t, 8192, 768, 768,
                                                    se_b2, x, out, nullptr);
    // attention block
    lnorm<<<8192, 256, 0, stream>>>(out, n1g, n1b, xb);
    gemm4<EPI_QKV><<<dim3(64, 18), 256, 0, stream>>>(xb, wqt, 8192, 2304, 768,
                                                     bqkv, nullptr, nullptr, q_);
    flash_attn<<<dim3(8, 12, 8), 256, 0, stream>>>(q_, k_, v_, o_);
    gemm4<EPI_RES><<<dim3(64, 6), 256, 0, stream>>>(o_, wot, 8192, 768, 768,
                                                    bo, out, out, nullptr);
    // FFN block
    lnorm<<<8192, 256, 0, stream>>>(out, n2g, n2b, xb);
    gemm4<EPI_GELU><<<dim3(64, 24), 256, 0, stream>>>(xb, g1t, 8192, 3072, 768,
                                                      gb1, nullptr, nullptr, hff);
    // FFN2 split-K=2: atomicAdd partials onto out (already holds residual)
    gemm4<EPI_RESK><<<dim3(64, 6, 2), 256, 0, stream>>>(hff, g2t, 8192, 768, 3072,
                                                        gb2, nullptr, out, nullptr);
}

// Round 16
// 391.854 us; speedup vs baseline: 1.0971x; 1.0717x over previous
//
#include <hip/hip_runtime.h>
#include <hip/hip_bf16.h>

typedef unsigned short ushort;
typedef __attribute__((ext_vector_type(8))) __bf16 bf16x8;
typedef __attribute__((ext_vector_type(4))) float f32x4;
typedef __attribute__((ext_vector_type(8))) ushort ushort8;

__device__ inline ushort f2bf(float f) {
    union { float f; unsigned u; } a{f};
    unsigned r = a.u + 0x7FFFu + ((a.u >> 16) & 1u);
    return (ushort)(r >> 16);
}
__device__ inline float gelu_f(float x) {
    return 0.5f * x * (1.f + erff(x * 0.70710678118654752f));
}

// ---------------- fused prologue: transposes + rowstat + precomp + init ----
// blocks 0..7487   : weight transposes [K,N] fp32 -> [N,K] bf16 (7 tasks)
// blocks 7488..15679 : rowstat (bf16 copy of x + row sum-of-squares)
// blocks 15680..15682: precomp_ac (fold dp/se_w1 -> rank-1 vectors)
// blocks 15683..15714: zero meanv
// block 15715       : concat qkv bias
__global__ void prep_all(const float* __restrict__ se_w2, ushort* __restrict__ sw2t,
                         const float* __restrict__ wq, ushort* __restrict__ wqt,
                         const float* __restrict__ wk, ushort* __restrict__ wkt,
                         const float* __restrict__ wv, ushort* __restrict__ wvt,
                         const float* __restrict__ wo, ushort* __restrict__ wot,
                         const float* __restrict__ gw1, ushort* __restrict__ g1t,
                         const float* __restrict__ gw2, ushort* __restrict__ g2t,
                         const float* __restrict__ x, ushort* __restrict__ xb,
                         float* __restrict__ sq,
                         const float* __restrict__ bq, const float* __restrict__ bk,
                         const float* __restrict__ bv, float* __restrict__ bqkv,
                         float* __restrict__ meanv,
                         const float* __restrict__ dp_w, const float* __restrict__ dp_b,
                         const float* __restrict__ se_w1, const float* __restrict__ se_b1,
                         float* __restrict__ Avec, float* __restrict__ Cvec) {
    __shared__ float tile[32][33];
    __shared__ float wsum[4];
    int bid = blockIdx.x;
    int tid = threadIdx.x;
    if (bid < 7488) {
        const float* Wm; ushort* Wt; int K, N, kx, ny;
        if (bid < 2880) {
            int task = bid / 576, tt = bid % 576;
            kx = tt % 24; ny = tt / 24; K = 768; N = 768;
            switch (task) {
                case 0: Wm = se_w2; Wt = sw2t; break;
                case 1: Wm = wq; Wt = wqt; break;
                case 2: Wm = wk; Wt = wkt; break;
                case 3: Wm = wv; Wt = wvt; break;
                default: Wm = wo; Wt = wot; break;
            }
        } else if (bid < 5184) {
            int tt = bid - 2880; kx = tt % 24; ny = tt / 24; K = 768; N = 3072;
            Wm = gw1; Wt = g1t;
        } else {
            int tt = bid - 5184; kx = tt % 96; ny = tt / 96; K = 3072; N = 768;
            Wm = gw2; Wt = g2t;
        }
        int k0 = kx * 32, n0 = ny * 32;
        int tx = tid & 31, ty = tid >> 5;
        #pragma unroll
        for (int r = ty; r < 32; r += 8) tile[r][tx] = Wm[(size_t)(k0 + r) * N + n0 + tx];
        __syncthreads();
        #pragma unroll
        for (int r = ty; r < 32; r += 8) Wt[(size_t)(n0 + r) * K + k0 + tx] = f2bf(tile[tx][r]);
    } else if (bid < 15680) {
        int row = bid - 7488;
        const float* xr = x + (size_t)row * 768;
        ushort* xbr = xb + (size_t)row * 768;
        float s = 0.f;
        #pragma unroll
        for (int i = 0; i < 3; ++i) {
            float vv = xr[tid + i * 256];
            xbr[tid + i * 256] = f2bf(vv);
            s += vv * vv;
        }
        #pragma unroll
        for (int off = 1; off < 64; off <<= 1) s += __shfl_xor(s, off);
        if ((tid & 63) == 0) wsum[tid >> 6] = s;
        __syncthreads();
        if (tid == 0) sq[row] = wsum[0] + wsum[1] + wsum[2] + wsum[3];
    } else if (bid < 15683) {
        int o = (bid - 15680) * 256 + tid;
        float a = 0.f, c = 0.f;
        for (int i = 0; i < 192; ++i) {
            float w = se_w1[(size_t)i * 768 + o];
            a += dp_w[i] * w;
            c += dp_b[i] * w;
        }
        Avec[o] = a;
        Cvec[o] = c + se_b1[o];
    } else if (bid < 15715) {
        meanv[(bid - 15683) * 256 + tid] = 0.f;
    } else {
        for (int i = tid; i < 2304; i += 256) {
            float v = (i < 768) ? bq[i] : (i < 1536 ? bk[i - 768] : bv[i - 1536]);
            bqkv[i] = v;
        }
    }
}

// ---------------- spatial h generation (rank-1 + gelu) ---------------------
__global__ void hgen(const float* __restrict__ mean_acc, const float* __restrict__ Avec,
                     const float* __restrict__ Cvec, ushort* __restrict__ h) {
    int row = blockIdx.x;
    float md = mean_acc[row] * (1.f / 1024.f);
    int t = threadIdx.x;
    #pragma unroll
    for (int i = 0; i < 3; ++i) {
        int o = t + i * 256;
        h[(size_t)row * 768 + o] = f2bf(gelu_f(md * Avec[o] + Cvec[o]));
    }
}

// ---------------- layernorm fp32 -> bf16 -----------------------------------
__global__ void lnorm(const float* __restrict__ xin, const float* __restrict__ g,
                      const float* __restrict__ b, ushort* __restrict__ xn) {
    int row = blockIdx.x;
    const float* xr = xin + (size_t)row * 768;
    int t = threadIdx.x;
    float v[3];
    float s = 0.f, s2 = 0.f;
    #pragma unroll
    for (int i = 0; i < 3; ++i) {
        v[i] = xr[t + i * 256];
        s += v[i];
        s2 += v[i] * v[i];
    }
    #pragma unroll
    for (int off = 1; off < 64; off <<= 1) { s += __shfl_xor(s, off); s2 += __shfl_xor(s2, off); }
    __shared__ float a0[4], a1[4];
    if ((t & 63) == 0) { a0[t >> 6] = s; a1[t >> 6] = s2; }
    __syncthreads();
    s = a0[0] + a0[1] + a0[2] + a0[3];
    s2 = a1[0] + a1[1] + a1[2] + a1[3];
    float mu = s * (1.f / 768.f);
    float var = s2 * (1.f / 768.f) - mu * mu;
    float rs = rsqrtf(var + 1e-5f);
    #pragma unroll
    for (int i = 0; i < 3; ++i) {
        int o = t + i * 256;
        xn[(size_t)row * 768 + o] = f2bf((v[i] - mu) * rs * g[o] + b[o]);
    }
}

// ---------------- MFMA GEMM (2-phase, 128-tile): used for Gram only --------
#define BM 128
#define BK 32

enum { EPI_BF16 = 0, EPI_GELU = 1, EPI_RES = 2, EPI_GRAM = 3, EPI_QKV = 4, EPI_RESK = 5 };

template <int EPI, int BNT>
__launch_bounds__(256, BNT == 64 ? 4 : 2)
__global__ void gemm_bt(const ushort* __restrict__ A, const ushort* __restrict__ Bt,
                        int M, int N, int K,
                        const float* __restrict__ bias,
                        const float* res, float* outf,
                        ushort* __restrict__ outh,
                        const float* __restrict__ sq, float* __restrict__ mean_acc) {
    __shared__ __align__(16) ushort As[2][BM * BK];
    __shared__ __align__(16) ushort Bs[2][BNT * BK];

    unsigned gx = gridDim.x, gy = gridDim.y;
    unsigned flat = blockIdx.x + gx * (blockIdx.y + gy * blockIdx.z);
    unsigned total = gx * gy * gridDim.z;
    unsigned chunk = total >> 3;
    flat = (flat & 7) * chunk + (flat >> 3);
    unsigned bx = flat % gx;
    unsigned rem = flat / gx;
    unsigned by = rem % gy;
    unsigned bz = rem / gy;

    int m0 = bx * BM;
    int n0 = by * BNT;
    if (EPI == EPI_GRAM) {
        A += (size_t)bz * 1024 * 768;
        Bt = A;
        sq += bz * 1024;
        mean_acc += bz * 1024;
    }
    int t = threadIdx.x, w = t >> 6, l = t & 63;
    int lg = l >> 4, li = l & 15;
    constexpr int MI = (BNT == 128) ? 4 : 2;
    int wm = (BNT == 128) ? (w >> 1) * 64 : w * 32;
    int wn = (BNT == 128) ? (w & 1) * 64 : 0;

    int srow = l >> 2, scol = (l & 3) * 8;
    const ushort* agp0 = A + (size_t)(m0 + (2 * w) * 16 + srow) * K + scol;
    const ushort* agp1 = A + (size_t)(m0 + (2 * w + 1) * 16 + srow) * K + scol;
    const ushort* bgp0;
    const ushort* bgp1 = nullptr;
    ushort* la0 = &As[0][(2 * w) * 16 * BK];
    ushort* lb0;
    if (BNT == 128) {
        bgp0 = Bt + (size_t)(n0 + (2 * w) * 16 + srow) * K + scol;
        bgp1 = Bt + (size_t)(n0 + (2 * w + 1) * 16 + srow) * K + scol;
        lb0 = &Bs[0][(2 * w) * 16 * BK];
    } else {
        bgp0 = Bt + (size_t)(n0 + w * 16 + srow) * K + scol;
        lb0 = &Bs[0][w * 16 * BK];
    }

    f32x4 acc[MI][4] = {};

    auto stage = [&](int buf, int kt) {
        size_t ko = (size_t)kt * BK;
        ushort* la = la0 + buf * (BM * BK);
        ushort* lb = lb0 + buf * (BNT * BK);
        __builtin_amdgcn_global_load_lds((const __attribute__((address_space(1))) void*)(agp0 + ko),
                                         (__attribute__((address_space(3))) void*)la, 16, 0, 0);
        __builtin_amdgcn_global_load_lds((const __attribute__((address_space(1))) void*)(agp1 + ko),
                                         (__attribute__((address_space(3))) void*)(la + 16 * BK), 16, 0, 0);
        __builtin_amdgcn_global_load_lds((const __attribute__((address_space(1))) void*)(bgp0 + ko),
                                         (__attribute__((address_space(3))) void*)lb, 16, 0, 0);
        if (BNT == 128)
            __builtin_amdgcn_global_load_lds((const __attribute__((address_space(1))) void*)(bgp1 + ko),
                                             (__attribute__((address_space(3))) void*)(lb + 16 * BK), 16, 0, 0);
    };

    int nk = K / BK;
    stage(0, 0);
    __syncthreads();
    int buf = 0;
    for (int kt = 0; kt < nk; ++kt) {
        if (kt + 1 < nk) stage(buf ^ 1, kt + 1);
        bf16x8 af[MI], bfr[4];
        #pragma unroll
        for (int i = 0; i < MI; ++i)
            af[i] = *reinterpret_cast<const bf16x8*>(&As[buf][(wm + i * 16 + li) * BK + lg * 8]);
        #pragma unroll
        for (int i = 0; i < 4; ++i)
            bfr[i] = *reinterpret_cast<const bf16x8*>(&Bs[buf][(wn + i * 16 + li) * BK + lg * 8]);
        #pragma unroll
        for (int mi = 0; mi < MI; ++mi)
            #pragma unroll
            for (int ni = 0; ni < 4; ++ni)
                acc[mi][ni] = __builtin_amdgcn_mfma_f32_16x16x32_bf16(af[mi], bfr[ni], acc[mi][ni], 0, 0, 0);
        __syncthreads();
        buf ^= 1;
    }

    #pragma unroll
    for (int mi = 0; mi < MI; ++mi) {
        #pragma unroll
        for (int r = 0; r < 4; ++r) {
            int row = m0 + wm + mi * 16 + lg * 4 + r;
            if (EPI == EPI_GRAM) {
                float si = sq[row];
                float s = 0.f;
                #pragma unroll
                for (int ni = 0; ni < 4; ++ni) {
                    int col = n0 + wn + ni * 16 + li;
                    float d2 = si + sq[col] - 2.f * acc[mi][ni][r];
                    s += sqrtf(fmaxf(d2, 0.f));
                }
                s += __shfl_xor(s, 1); s += __shfl_xor(s, 2);
                s += __shfl_xor(s, 4); s += __shfl_xor(s, 8);
                if (li == 0) atomicAdd(&mean_acc[row], s);
            } else {
                #pragma unroll
                for (int ni = 0; ni < 4; ++ni) {
                    int col = n0 + wn + ni * 16 + li;
                    float v = acc[mi][ni][r] + bias[col];
                    if (EPI == EPI_BF16) outh[(size_t)row * N + col] = f2bf(v);
                    if (EPI == EPI_GELU) outh[(size_t)row * N + col] = f2bf(gelu_f(v));
                    if (EPI == EPI_RES) outf[(size_t)row * N + col] = res[(size_t)row * N + col] + v;
                    if (EPI == EPI_QKV) {
                        int which = col / 768;
                        int c2 = col - which * 768;
                        outh[(size_t)which * (8192 * 768) + (size_t)row * 768 + c2] = f2bf(v);
                    }
                }
            }
        }
    }
}

// ---------------- gemm4p: 128x128, m-split XCD, 3 blocks/CU, PIPELINED -----
// 4 waves, BK=32, 3-slot LDS ring (48 KB), staged 2 iters ahead, counted
// vmcnt(4), single barrier per K-step (trailing barrier proven redundant),
// LDS XOR swizzle both-sides (conflicts measured 0). EPI_RESK: split-K=2,
// fp32 atomicAdd onto outf (holds residual); bias added by split 0 only.
template <int EPI>
__launch_bounds__(256, 3)
__global__ void gemm4(const ushort* __restrict__ A, const ushort* __restrict__ Bt,
                      int M, int N, int K,
                      const float* __restrict__ bias,
                      const float* res, float* outf, ushort* __restrict__ outh) {
    __shared__ __align__(16) ushort As[3][128 * 32];
    __shared__ __align__(16) ushort Bs[3][128 * 32];

    unsigned gx = gridDim.x, gy = gridDim.y;
    unsigned orig = blockIdx.x + gx * (blockIdx.y + gy * blockIdx.z);
    unsigned xcd = orig & 7;
    unsigned q = orig >> 3;
    unsigned mpg = gx >> 3;
    unsigned mloc = q % mpg;
    unsigned rest = q / mpg;
    unsigned n = rest % gy;
    unsigned split = rest / gy;              // 0 unless gridDim.z == 2
    int m0 = (xcd * mpg + mloc) * 128;
    int n0 = n * 128;
    int Keff = (EPI == EPI_RESK) ? (K >> 1) : K;
    int kbase = (EPI == EPI_RESK) ? (int)split * Keff : 0;

    int t = threadIdx.x, w = t >> 6, l = t & 63;
    int lg = l >> 4, li = l & 15;
    int wm = (w >> 1) * 64, wn = (w & 1) * 64;

    int srow = l >> 2;
    int scol = ((l & 3) ^ ((l >> 3) & 3)) * 8;
    const ushort* agp0 = A + (size_t)(m0 + (2 * w) * 16 + srow) * K + kbase + scol;
    const ushort* agp1 = A + (size_t)(m0 + (2 * w + 1) * 16 + srow) * K + kbase + scol;
    const ushort* bgp0 = Bt + (size_t)(n0 + (2 * w) * 16 + srow) * K + kbase + scol;
    const ushort* bgp1 = Bt + (size_t)(n0 + (2 * w + 1) * 16 + srow) * K + kbase + scol;

    f32x4 acc[4][4] = {};

    auto stage = [&](int buf, int kt) {
        size_t ko = (size_t)kt * 32;
        ushort* la = &As[buf][(2 * w) * 16 * 32];
        ushort* lb = &Bs[buf][(2 * w) * 16 * 32];
        __builtin_amdgcn_global_load_lds((const __attribute__((address_space(1))) void*)(agp0 + ko),
                                         (__attribute__((address_space(3))) void*)la, 16, 0, 0);
        __builtin_amdgcn_global_load_lds((const __attribute__((address_space(1))) void*)(agp1 + ko),
                                         (__attribute__((address_space(3))) void*)(la + 16 * 32), 16, 0, 0);
        __builtin_amdgcn_global_load_lds((const __attribute__((address_space(1))) void*)(bgp0 + ko),
                                         (__attribute__((address_space(3))) void*)lb, 16, 0, 0);
        __builtin_amdgcn_global_load_lds((const __attribute__((address_space(1))) void*)(bgp1 + ko),
                                         (__attribute__((address_space(3))) void*)(lb + 16 * 32), 16, 0, 0);
    };

    int nk = Keff / 32;
    stage(0, 0);
    stage(1, 1);
    int rdsw = (lg ^ ((li >> 1) & 3)) * 8;   // swizzled read column
    for (int kt = 0; kt < nk; ++kt) {
        int buf = kt % 3;
        if (kt + 1 < nk) asm volatile("s_waitcnt vmcnt(4)" ::: "memory");
        else             asm volatile("s_waitcnt vmcnt(0)" ::: "memory");
        asm volatile("s_barrier" ::: "memory");
        __builtin_amdgcn_sched_barrier(0);
        bf16x8 af[4], bfr[4];
        #pragma unroll
        for (int i = 0; i < 4; ++i) {
            af[i] = *reinterpret_cast<const bf16x8*>(&As[buf][(wm + i * 16 + li) * 32 + rdsw]);
            bfr[i] = *reinterpret_cast<const bf16x8*>(&Bs[buf][(wn + i * 16 + li) * 32 + rdsw]);
        }
        __builtin_amdgcn_s_setprio(1);
        #pragma unroll
        for (int mi = 0; mi < 4; ++mi)
            #pragma unroll
            for (int ni = 0; ni < 4; ++ni)
                acc[mi][ni] = __builtin_amdgcn_mfma_f32_16x16x32_bf16(af[mi], bfr[ni], acc[mi][ni], 0, 0, 0);
        __builtin_amdgcn_s_setprio(0);
        if (kt + 2 < nk) stage((kt + 2) % 3, kt + 2);
    }

    #pragma unroll
    for (int mi = 0; mi < 4; ++mi) {
        #pragma unroll
        for (int r = 0; r < 4; ++r) {
            int row = m0 + wm + mi * 16 + lg * 4 + r;
            #pragma unroll
            for (int ni = 0; ni < 4; ++ni) {
                int col = n0 + wn + ni * 16 + li;
                if (EPI == EPI_RESK) {
                    float v = acc[mi][ni][r] + (split == 0 ? bias[col] : 0.f);
                    atomicAdd(&outf[(size_t)row * N + col], v);
                } else {
                    float v = acc[mi][ni][r] + bias[col];
                    if (EPI == EPI_GELU) outh[(size_t)row * N + col] = f2bf(gelu_f(v));
                    if (EPI == EPI_RES)  outf[(size_t)row * N + col] = res[(size_t)row * N + col] + v;
                    if (EPI == EPI_QKV) {
                        int which = col / 768;
                        int c2 = col - which * 768;
                        outh[(size_t)which * (8192 * 768) + (size_t)row * 768 + c2] = f2bf(v);
                    }
                }
            }
        }
    }
}

// ---------------- flash attention v8: ones-MFMA ell + defer-max + setprio --
// grid (8, 12, 8); 4 waves; wave w owns q-rows [qt*128 + w*32, +32) as 2 frags
__launch_bounds__(256, 3)
__global__ void flash_attn(const ushort* __restrict__ q, const ushort* __restrict__ k,
                           const ushort* __restrict__ v, ushort* __restrict__ o) {
    int flat = blockIdx.x + 8 * (blockIdx.y + 12 * blockIdx.z);
    flat = (flat & 7) * 96 + (flat >> 3);
    int qt = flat & 7;
    int rem = flat >> 3;
    int h = rem % 12;
    int b = rem / 12;

    int t = threadIdx.x, w = t >> 6, l = t & 63;
    int lg = l >> 4, li = l & 15;

    __shared__ __align__(16) ushort Vt[2][64][72];  // V^T tile, stride 144B
    __shared__ __align__(16) ushort P[4][32][72];   // per-wave P[q][kv]

    const size_t hoff = (size_t)h * 64;
    const size_t bbase = (size_t)b * 1024 * 768;

    bf16x8 qf[2][2];
    #pragma unroll
    for (int f = 0; f < 2; ++f) {
        int qrow = qt * 128 + w * 32 + f * 16 + li;
        const ushort* qp = &q[bbase + (size_t)qrow * 768 + hoff];
        qf[f][0] = *reinterpret_cast<const bf16x8*>(qp + lg * 8);
        qf[f][1] = *reinterpret_cast<const bf16x8*>(qp + 32 + lg * 8);
    }

    bf16x8 onesf;
    #pragma unroll
    for (int i = 0; i < 8; ++i) onesf[i] = (__bf16)1.0f;

    float m_[2][4];
    f32x4 oacc[2][4];
    f32x4 oell[2];
    #pragma unroll
    for (int f = 0; f < 2; ++f) {
        #pragma unroll
        for (int r = 0; r < 4; ++r) m_[f][r] = -1e30f;
        oell[f] = f32x4{0.f, 0.f, 0.f, 0.f};
        #pragma unroll
        for (int n = 0; n < 4; ++n) oacc[f][n] = f32x4{0.f, 0.f, 0.f, 0.f};
    }

    int vrow = t & 63;
    int vc = t >> 6;
    const ushort* vbase = &v[bbase + hoff];

    ushort8 vv0 = *reinterpret_cast<const ushort8*>(&vbase[(size_t)vrow * 768 + vc * 8]);
    ushort8 vv1 = *reinterpret_cast<const ushort8*>(&vbase[(size_t)vrow * 768 + (vc + 4) * 8]);

    for (int jt = 0; jt < 16; ++jt) {
        int j0 = jt * 64, buf = jt & 1;
        #pragma unroll
        for (int i = 0; i < 8; ++i) Vt[buf][vc * 8 + i][vrow] = vv0[i];
        #pragma unroll
        for (int i = 0; i < 8; ++i) Vt[buf][(vc + 4) * 8 + i][vrow] = vv1[i];
        if (jt < 15) {
            vv0 = *reinterpret_cast<const ushort8*>(&vbase[(size_t)(j0 + 64 + vrow) * 768 + vc * 8]);
            vv1 = *reinterpret_cast<const ushort8*>(&vbase[(size_t)(j0 + 64 + vrow) * 768 + (vc + 4) * 8]);
        }
        bf16x8 kf0[4], kf1[4];
        #pragma unroll
        for (int jj = 0; jj < 4; ++jj) {
            const ushort* kp = &k[bbase + (size_t)(j0 + jj * 16 + li) * 768 + hoff];
            kf0[jj] = *reinterpret_cast<const bf16x8*>(kp + lg * 8);
            kf1[jj] = *reinterpret_cast<const bf16x8*>(kp + 32 + lg * 8);
        }
        f32x4 s[2][4];
        __builtin_amdgcn_s_setprio(1);
        #pragma unroll
        for (int jj = 0; jj < 4; ++jj)
            #pragma unroll
            for (int f = 0; f < 2; ++f) {
                f32x4 a = {0.f, 0.f, 0.f, 0.f};
                a = __builtin_amdgcn_mfma_f32_16x16x32_bf16(qf[f][0], kf0[jj], a, 0, 0, 0);
                a = __builtin_amdgcn_mfma_f32_16x16x32_bf16(qf[f][1], kf1[jj], a, 0, 0, 0);
                s[f][jj] = a * 0.125f;
            }
        __builtin_amdgcn_s_setprio(0);
        #pragma unroll
        for (int f = 0; f < 2; ++f) {
            float mt[4];
            #pragma unroll
            for (int r = 0; r < 4; ++r)
                mt[r] = fmaxf(fmaxf(s[f][0][r], s[f][1][r]), fmaxf(s[f][2][r], s[f][3][r]));
            #pragma unroll
            for (int r = 0; r < 4; ++r) {
                mt[r] = fmaxf(mt[r], __shfl_xor(mt[r], 1));
                mt[r] = fmaxf(mt[r], __shfl_xor(mt[r], 2));
                mt[r] = fmaxf(mt[r], __shfl_xor(mt[r], 4));
                mt[r] = fmaxf(mt[r], __shfl_xor(mt[r], 8));
            }
            bool need = (mt[0] > m_[f][0] + 8.f) | (mt[1] > m_[f][1] + 8.f) |
                        (mt[2] > m_[f][2] + 8.f) | (mt[3] > m_[f][3] + 8.f);
            if (__any(need)) {
                #pragma unroll
                for (int r = 0; r < 4; ++r) {
                    float mn = fmaxf(m_[f][r], mt[r]);
                    float al = __expf(m_[f][r] - mn);
                    m_[f][r] = mn;
                    #pragma unroll
                    for (int n = 0; n < 4; ++n) oacc[f][n][r] *= al;
                    oell[f][r] *= al;
                }
            }
            #pragma unroll
            for (int jj = 0; jj < 4; ++jj)
                #pragma unroll
                for (int r = 0; r < 4; ++r)
                    P[w][f * 16 + lg * 4 + r][jj * 16 + li] = f2bf(__expf(s[f][jj][r] - m_[f][r]));
        }
        __syncthreads();
        bf16x8 pf[2][2];
        #pragma unroll
        for (int f = 0; f < 2; ++f) {
            pf[f][0] = *reinterpret_cast<const bf16x8*>(&P[w][f * 16 + li][lg * 8]);
            pf[f][1] = *reinterpret_cast<const bf16x8*>(&P[w][f * 16 + li][32 + lg * 8]);
        }
        __builtin_amdgcn_s_setprio(1);
        #pragma unroll
        for (int f = 0; f < 2; ++f) {
            oell[f] = __builtin_amdgcn_mfma_f32_16x16x32_bf16(pf[f][0], onesf, oell[f], 0, 0, 0);
            oell[f] = __builtin_amdgcn_mfma_f32_16x16x32_bf16(pf[f][1], onesf, oell[f], 0, 0, 0);
        }
        #pragma unroll
        for (int n = 0; n < 4; ++n) {
            bf16x8 vf0 = *reinterpret_cast<const bf16x8*>(&Vt[buf][n * 16 + li][lg * 8]);
            bf16x8 vf1 = *reinterpret_cast<const bf16x8*>(&Vt[buf][n * 16 + li][32 + lg * 8]);
            #pragma unroll
            for (int f = 0; f < 2; ++f) {
                oacc[f][n] = __builtin_amdgcn_mfma_f32_16x16x32_bf16(pf[f][0], vf0, oacc[f][n], 0, 0, 0);
                oacc[f][n] = __builtin_amdgcn_mfma_f32_16x16x32_bf16(pf[f][1], vf1, oacc[f][n], 0, 0, 0);
            }
        }
        __builtin_amdgcn_s_setprio(0);
    }
    #pragma unroll
    for (int f = 0; f < 2; ++f)
        #pragma unroll
        for (int n = 0; n < 4; ++n)
            #pragma unroll
            for (int r = 0; r < 4; ++r) {
                int row = qt * 128 + w * 32 + f * 16 + lg * 4 + r;
                o[bbase + (size_t)row * 768 + hoff + n * 16 + li] = f2bf(oacc[f][n][r] / oell[f][r]);
            }
}

// ---------------------------------------------------------------------------
extern "C" void kernel_launch(void* const* d_in, const int* in_sizes, int n_in,
                              void* d_out, int out_size, void* d_ws, size_t ws_size,
                              hipStream_t stream) {
    const float* x = (const float*)d_in[0];
    const float* dp_w = (const float*)d_in[1];
    const float* dp_b = (const float*)d_in[2];
    const float* se_w1 = (const float*)d_in[3];
    const float* se_b1 = (const float*)d_in[4];
    const float* se_w2 = (const float*)d_in[5];
    const float* se_b2 = (const float*)d_in[6];
    const float* wq = (const float*)d_in[7];  const float* bq = (const float*)d_in[8];
    const float* wk = (const float*)d_in[9];  const float* bk = (const float*)d_in[10];
    const float* wv = (const float*)d_in[11]; const float* bv = (const float*)d_in[12];
    const float* wo = (const float*)d_in[13]; const float* bo = (const float*)d_in[14];
    const float* gw1 = (const float*)d_in[15]; const float* gb1 = (const float*)d_in[16];
    const float* gw2 = (const float*)d_in[17]; const float* gb2 = (const float*)d_in[18];
    const float* n1g = (const float*)d_in[19]; const float* n1b = (const float*)d_in[20];
    const float* n2g = (const float*)d_in[21]; const float* n2b = (const float*)d_in[22];
    float* out = (float*)d_out;

    constexpr size_t SZ_ACT = (size_t)8192 * 768 * 2;  // bytes per bf16 activation
    char* W = (char*)d_ws;
    ushort* xb = (ushort*)(W);                  // bf16 x; later reused as xn
    ushort* q_ = (ushort*)(W + SZ_ACT);
    ushort* k_ = (ushort*)(W + 2 * SZ_ACT);
    ushort* v_ = (ushort*)(W + 3 * SZ_ACT);
    ushort* o_ = (ushort*)(W + 4 * SZ_ACT);
    ushort* hsp = q_;
    ushort* hff = q_;
    ushort* wqt = (ushort*)(W + 5 * SZ_ACT);    // contiguous qkv weight [2304][768]
    ushort* wkt = wqt + (size_t)768 * 768;
    ushort* wvt = wkt + (size_t)768 * 768;
    ushort* wot = wvt + (size_t)768 * 768;
    ushort* sw2t = wot + (size_t)768 * 768;
    ushort* g1t = sw2t + (size_t)768 * 768;
    ushort* g2t = g1t + (size_t)768 * 3072;
    float* sqv = (float*)(g2t + (size_t)3072 * 768);
    float* meanv = sqv + 8192;
    float* Avec = meanv + 8192;
    float* Cvec = Avec + 768;
    float* bqkv = Cvec + 768;                   // concat bias [2304]

    // fused prologue: 7 transposes + rowstat + precomp + meanv=0 + bqkv concat
    prep_all<<<15716, 256, 0, stream>>>(se_w2, sw2t, wq, wqt, wk, wkt, wv, wvt,
                                        wo, wot, gw1, g1t, gw2, g2t,
                                        x, xb, sqv, bq, bk, bv, bqkv, meanv,
                                        dp_w, dp_b, se_w1, se_b1, Avec, Cvec);

    // Gram -> distance row-sums (batch-per-XCD, L2-resident)
    gemm_bt<EPI_GRAM, 128><<<dim3(8, 8, 8), 256, 0, stream>>>(xb, xb, 1024, 1024, 768,
                                                              nullptr, nullptr, nullptr, nullptr, sqv, meanv);
    hgen<<<8192, 256, 0, stream>>>(meanv, Avec, Cvec, hsp);
    // x = x + h @ se_w2 + se_b2  -> d_out (fp32 residual stream)
    gemm4<EPI_RES><<<dim3(64, 6), 256, 0, stream>>>(hsp, sw2t, 8192, 768, 768,
                                                    se_b2, x, out, nullptr);
    // attention block
    lnorm<<<8192, 256, 0, stream>>>(out, n1g, n1b, xb);
    gemm4<EPI_QKV><<<dim3(64, 18), 256, 0, stream>>>(xb, wqt, 8192, 2304, 768,
                                                     bqkv, nullptr, nullptr, q_);
    flash_attn<<<dim3(8, 12, 8), 256, 0, stream>>>(q_, k_, v_, o_);
    gemm4<EPI_RES><<<dim3(64, 6), 256, 0, stream>>>(o_, wot, 8192, 768, 768,
                                                    bo, out, out, nullptr);
    // FFN block
    lnorm<<<8192, 256, 0, stream>>>(out, n2g, n2b, xb);
    gemm4<EPI_GELU><<<dim3(64, 24), 256, 0, stream>>>(xb, g1t, 8192, 3072, 768,
                                                      gb1, nullptr, nullptr, hff);
    // FFN2 split-K=2: atomicAdd partials onto out (already holds residual)
    gemm4<EPI_RESK><<<dim3(64, 6, 2), 256, 0, stream>>>(hff, g2t, 8192, 768, 3072,
                                                        gb2, nullptr, out, nullptr);
}

// Round 17
// 390.001 us; speedup vs baseline: 1.1024x; 1.0048x over previous
//
#include <hip/hip_runtime.h>
#include <hip/hip_bf16.h>

typedef unsigned short ushort;
typedef __attribute__((ext_vector_type(8))) __bf16 bf16x8;
typedef __attribute__((ext_vector_type(4))) float f32x4;
typedef __attribute__((ext_vector_type(8))) ushort ushort8;

__device__ inline ushort f2bf(float f) {
    union { float f; unsigned u; } a{f};
    unsigned r = a.u + 0x7FFFu + ((a.u >> 16) & 1u);
    return (ushort)(r >> 16);
}
__device__ inline float gelu_f(float x) {
    return 0.5f * x * (1.f + erff(x * 0.70710678118654752f));
}

// ---------------- fused prologue: transposes + rowstat + precomp + init ----
__global__ void prep_all(const float* __restrict__ se_w2, ushort* __restrict__ sw2t,
                         const float* __restrict__ wq, ushort* __restrict__ wqt,
                         const float* __restrict__ wk, ushort* __restrict__ wkt,
                         const float* __restrict__ wv, ushort* __restrict__ wvt,
                         const float* __restrict__ wo, ushort* __restrict__ wot,
                         const float* __restrict__ gw1, ushort* __restrict__ g1t,
                         const float* __restrict__ gw2, ushort* __restrict__ g2t,
                         const float* __restrict__ x, ushort* __restrict__ xb,
                         float* __restrict__ sq,
                         const float* __restrict__ bq, const float* __restrict__ bk,
                         const float* __restrict__ bv, float* __restrict__ bqkv,
                         float* __restrict__ meanv,
                         const float* __restrict__ dp_w, const float* __restrict__ dp_b,
                         const float* __restrict__ se_w1, const float* __restrict__ se_b1,
                         float* __restrict__ Avec, float* __restrict__ Cvec) {
    __shared__ float tile[32][33];
    __shared__ float wsum[4];
    int bid = blockIdx.x;
    int tid = threadIdx.x;
    if (bid < 7488) {
        const float* Wm; ushort* Wt; int K, N, kx, ny;
        if (bid < 2880) {
            int task = bid / 576, tt = bid % 576;
            kx = tt % 24; ny = tt / 24; K = 768; N = 768;
            switch (task) {
                case 0: Wm = se_w2; Wt = sw2t; break;
                case 1: Wm = wq; Wt = wqt; break;
                case 2: Wm = wk; Wt = wkt; break;
                case 3: Wm = wv; Wt = wvt; break;
                default: Wm = wo; Wt = wot; break;
            }
        } else if (bid < 5184) {
            int tt = bid - 2880; kx = tt % 24; ny = tt / 24; K = 768; N = 3072;
            Wm = gw1; Wt = g1t;
        } else {
            int tt = bid - 5184; kx = tt % 96; ny = tt / 96; K = 3072; N = 768;
            Wm = gw2; Wt = g2t;
        }
        int k0 = kx * 32, n0 = ny * 32;
        int tx = tid & 31, ty = tid >> 5;
        #pragma unroll
        for (int r = ty; r < 32; r += 8) tile[r][tx] = Wm[(size_t)(k0 + r) * N + n0 + tx];
        __syncthreads();
        #pragma unroll
        for (int r = ty; r < 32; r += 8) Wt[(size_t)(n0 + r) * K + k0 + tx] = f2bf(tile[tx][r]);
    } else if (bid < 15680) {
        int row = bid - 7488;
        const float* xr = x + (size_t)row * 768;
        ushort* xbr = xb + (size_t)row * 768;
        float s = 0.f;
        #pragma unroll
        for (int i = 0; i < 3; ++i) {
            float vv = xr[tid + i * 256];
            xbr[tid + i * 256] = f2bf(vv);
            s += vv * vv;
        }
        #pragma unroll
        for (int off = 1; off < 64; off <<= 1) s += __shfl_xor(s, off);
        if ((tid & 63) == 0) wsum[tid >> 6] = s;
        __syncthreads();
        if (tid == 0) sq[row] = wsum[0] + wsum[1] + wsum[2] + wsum[3];
    } else if (bid < 15683) {
        int o = (bid - 15680) * 256 + tid;
        float a = 0.f, c = 0.f;
        for (int i = 0; i < 192; ++i) {
            float w = se_w1[(size_t)i * 768 + o];
            a += dp_w[i] * w;
            c += dp_b[i] * w;
        }
        Avec[o] = a;
        Cvec[o] = c + se_b1[o];
    } else if (bid < 15715) {
        meanv[(bid - 15683) * 256 + tid] = 0.f;
    } else {
        for (int i = tid; i < 2304; i += 256) {
            float v = (i < 768) ? bq[i] : (i < 1536 ? bk[i - 768] : bv[i - 1536]);
            bqkv[i] = v;
        }
    }
}

// ---------------- spatial h generation (rank-1 + gelu) ---------------------
__global__ void hgen(const float* __restrict__ mean_acc, const float* __restrict__ Avec,
                     const float* __restrict__ Cvec, ushort* __restrict__ h) {
    int row = blockIdx.x;
    float md = mean_acc[row] * (1.f / 1024.f);
    int t = threadIdx.x;
    #pragma unroll
    for (int i = 0; i < 3; ++i) {
        int o = t + i * 256;
        h[(size_t)row * 768 + o] = f2bf(gelu_f(md * Avec[o] + Cvec[o]));
    }
}

// ---------------- layernorm fp32 -> bf16 -----------------------------------
__global__ void lnorm(const float* __restrict__ xin, const float* __restrict__ g,
                      const float* __restrict__ b, ushort* __restrict__ xn) {
    int row = blockIdx.x;
    const float* xr = xin + (size_t)row * 768;
    int t = threadIdx.x;
    float v[3];
    float s = 0.f, s2 = 0.f;
    #pragma unroll
    for (int i = 0; i < 3; ++i) {
        v[i] = xr[t + i * 256];
        s += v[i];
        s2 += v[i] * v[i];
    }
    #pragma unroll
    for (int off = 1; off < 64; off <<= 1) { s += __shfl_xor(s, off); s2 += __shfl_xor(s2, off); }
    __shared__ float a0[4], a1[4];
    if ((t & 63) == 0) { a0[t >> 6] = s; a1[t >> 6] = s2; }
    __syncthreads();
    s = a0[0] + a0[1] + a0[2] + a0[3];
    s2 = a1[0] + a1[1] + a1[2] + a1[3];
    float mu = s * (1.f / 768.f);
    float var = s2 * (1.f / 768.f) - mu * mu;
    float rs = rsqrtf(var + 1e-5f);
    #pragma unroll
    for (int i = 0; i < 3; ++i) {
        int o = t + i * 256;
        xn[(size_t)row * 768 + o] = f2bf((v[i] - mu) * rs * g[o] + b[o]);
    }
}

// ---------------- MFMA GEMM (2-phase, 128-tile): used for Gram only --------
#define BM 128
#define BK 32

enum { EPI_BF16 = 0, EPI_GELU = 1, EPI_RES = 2, EPI_GRAM = 3, EPI_QKV = 4, EPI_RESK = 5 };

template <int EPI, int BNT>
__launch_bounds__(256, BNT == 64 ? 4 : 2)
__global__ void gemm_bt(const ushort* __restrict__ A, const ushort* __restrict__ Bt,
                        int M, int N, int K,
                        const float* __restrict__ bias,
                        const float* res, float* outf,
                        ushort* __restrict__ outh,
                        const float* __restrict__ sq, float* __restrict__ mean_acc) {
    __shared__ __align__(16) ushort As[2][BM * BK];
    __shared__ __align__(16) ushort Bs[2][BNT * BK];

    unsigned gx = gridDim.x, gy = gridDim.y;
    unsigned flat = blockIdx.x + gx * (blockIdx.y + gy * blockIdx.z);
    unsigned total = gx * gy * gridDim.z;
    unsigned chunk = total >> 3;
    flat = (flat & 7) * chunk + (flat >> 3);
    unsigned bx = flat % gx;
    unsigned rem = flat / gx;
    unsigned by = rem % gy;
    unsigned bz = rem / gy;

    int m0 = bx * BM;
    int n0 = by * BNT;
    if (EPI == EPI_GRAM) {
        A += (size_t)bz * 1024 * 768;
        Bt = A;
        sq += bz * 1024;
        mean_acc += bz * 1024;
    }
    int t = threadIdx.x, w = t >> 6, l = t & 63;
    int lg = l >> 4, li = l & 15;
    constexpr int MI = (BNT == 128) ? 4 : 2;
    int wm = (BNT == 128) ? (w >> 1) * 64 : w * 32;
    int wn = (BNT == 128) ? (w & 1) * 64 : 0;

    int srow = l >> 2, scol = (l & 3) * 8;
    const ushort* agp0 = A + (size_t)(m0 + (2 * w) * 16 + srow) * K + scol;
    const ushort* agp1 = A + (size_t)(m0 + (2 * w + 1) * 16 + srow) * K + scol;
    const ushort* bgp0;
    const ushort* bgp1 = nullptr;
    ushort* la0 = &As[0][(2 * w) * 16 * BK];
    ushort* lb0;
    if (BNT == 128) {
        bgp0 = Bt + (size_t)(n0 + (2 * w) * 16 + srow) * K + scol;
        bgp1 = Bt + (size_t)(n0 + (2 * w + 1) * 16 + srow) * K + scol;
        lb0 = &Bs[0][(2 * w) * 16 * BK];
    } else {
        bgp0 = Bt + (size_t)(n0 + w * 16 + srow) * K + scol;
        lb0 = &Bs[0][w * 16 * BK];
    }

    f32x4 acc[MI][4] = {};

    auto stage = [&](int buf, int kt) {
        size_t ko = (size_t)kt * BK;
        ushort* la = la0 + buf * (BM * BK);
        ushort* lb = lb0 + buf * (BNT * BK);
        __builtin_amdgcn_global_load_lds((const __attribute__((address_space(1))) void*)(agp0 + ko),
                                         (__attribute__((address_space(3))) void*)la, 16, 0, 0);
        __builtin_amdgcn_global_load_lds((const __attribute__((address_space(1))) void*)(agp1 + ko),
                                         (__attribute__((address_space(3))) void*)(la + 16 * BK), 16, 0, 0);
        __builtin_amdgcn_global_load_lds((const __attribute__((address_space(1))) void*)(bgp0 + ko),
                                         (__attribute__((address_space(3))) void*)lb, 16, 0, 0);
        if (BNT == 128)
            __builtin_amdgcn_global_load_lds((const __attribute__((address_space(1))) void*)(bgp1 + ko),
                                             (__attribute__((address_space(3))) void*)(lb + 16 * BK), 16, 0, 0);
    };

    int nk = K / BK;
    stage(0, 0);
    __syncthreads();
    int buf = 0;
    for (int kt = 0; kt < nk; ++kt) {
        if (kt + 1 < nk) stage(buf ^ 1, kt + 1);
        bf16x8 af[MI], bfr[4];
        #pragma unroll
        for (int i = 0; i < MI; ++i)
            af[i] = *reinterpret_cast<const bf16x8*>(&As[buf][(wm + i * 16 + li) * BK + lg * 8]);
        #pragma unroll
        for (int i = 0; i < 4; ++i)
            bfr[i] = *reinterpret_cast<const bf16x8*>(&Bs[buf][(wn + i * 16 + li) * BK + lg * 8]);
        #pragma unroll
        for (int mi = 0; mi < MI; ++mi)
            #pragma unroll
            for (int ni = 0; ni < 4; ++ni)
                acc[mi][ni] = __builtin_amdgcn_mfma_f32_16x16x32_bf16(af[mi], bfr[ni], acc[mi][ni], 0, 0, 0);
        __syncthreads();
        buf ^= 1;
    }

    #pragma unroll
    for (int mi = 0; mi < MI; ++mi) {
        #pragma unroll
        for (int r = 0; r < 4; ++r) {
            int row = m0 + wm + mi * 16 + lg * 4 + r;
            if (EPI == EPI_GRAM) {
                float si = sq[row];
                float s = 0.f;
                #pragma unroll
                for (int ni = 0; ni < 4; ++ni) {
                    int col = n0 + wn + ni * 16 + li;
                    float d2 = si + sq[col] - 2.f * acc[mi][ni][r];
                    s += sqrtf(fmaxf(d2, 0.f));
                }
                s += __shfl_xor(s, 1); s += __shfl_xor(s, 2);
                s += __shfl_xor(s, 4); s += __shfl_xor(s, 8);
                if (li == 0) atomicAdd(&mean_acc[row], s);
            } else {
                #pragma unroll
                for (int ni = 0; ni < 4; ++ni) {
                    int col = n0 + wn + ni * 16 + li;
                    float v = acc[mi][ni][r] + bias[col];
                    if (EPI == EPI_BF16) outh[(size_t)row * N + col] = f2bf(v);
                    if (EPI == EPI_GELU) outh[(size_t)row * N + col] = f2bf(gelu_f(v));
                    if (EPI == EPI_RES) outf[(size_t)row * N + col] = res[(size_t)row * N + col] + v;
                    if (EPI == EPI_QKV) {
                        int which = col / 768;
                        int c2 = col - which * 768;
                        outh[(size_t)which * (8192 * 768) + (size_t)row * 768 + c2] = f2bf(v);
                    }
                }
            }
        }
    }
}

// ---------------- gemm4p: 128x128, m-split XCD, 3 blocks/CU, PIPELINED -----
template <int EPI>
__launch_bounds__(256, 3)
__global__ void gemm4(const ushort* __restrict__ A, const ushort* __restrict__ Bt,
                      int M, int N, int K,
                      const float* __restrict__ bias,
                      const float* res, float* outf, ushort* __restrict__ outh) {
    __shared__ __align__(16) ushort As[3][128 * 32];
    __shared__ __align__(16) ushort Bs[3][128 * 32];

    unsigned gx = gridDim.x, gy = gridDim.y;
    unsigned orig = blockIdx.x + gx * (blockIdx.y + gy * blockIdx.z);
    unsigned xcd = orig & 7;
    unsigned q = orig >> 3;
    unsigned mpg = gx >> 3;
    unsigned mloc = q % mpg;
    unsigned rest = q / mpg;
    unsigned n = rest % gy;
    unsigned split = rest / gy;              // 0 unless gridDim.z == 2
    int m0 = (xcd * mpg + mloc) * 128;
    int n0 = n * 128;
    int Keff = (EPI == EPI_RESK) ? (K >> 1) : K;
    int kbase = (EPI == EPI_RESK) ? (int)split * Keff : 0;

    int t = threadIdx.x, w = t >> 6, l = t & 63;
    int lg = l >> 4, li = l & 15;
    int wm = (w >> 1) * 64, wn = (w & 1) * 64;

    int srow = l >> 2;
    int scol = ((l & 3) ^ ((l >> 3) & 3)) * 8;
    const ushort* agp0 = A + (size_t)(m0 + (2 * w) * 16 + srow) * K + kbase + scol;
    const ushort* agp1 = A + (size_t)(m0 + (2 * w + 1) * 16 + srow) * K + kbase + scol;
    const ushort* bgp0 = Bt + (size_t)(n0 + (2 * w) * 16 + srow) * K + kbase + scol;
    const ushort* bgp1 = Bt + (size_t)(n0 + (2 * w + 1) * 16 + srow) * K + kbase + scol;

    f32x4 acc[4][4] = {};

    auto stage = [&](int buf, int kt) {
        size_t ko = (size_t)kt * 32;
        ushort* la = &As[buf][(2 * w) * 16 * 32];
        ushort* lb = &Bs[buf][(2 * w) * 16 * 32];
        __builtin_amdgcn_global_load_lds((const __attribute__((address_space(1))) void*)(agp0 + ko),
                                         (__attribute__((address_space(3))) void*)la, 16, 0, 0);
        __builtin_amdgcn_global_load_lds((const __attribute__((address_space(1))) void*)(agp1 + ko),
                                         (__attribute__((address_space(3))) void*)(la + 16 * 32), 16, 0, 0);
        __builtin_amdgcn_global_load_lds((const __attribute__((address_space(1))) void*)(bgp0 + ko),
                                         (__attribute__((address_space(3))) void*)lb, 16, 0, 0);
        __builtin_amdgcn_global_load_lds((const __attribute__((address_space(1))) void*)(bgp1 + ko),
                                         (__attribute__((address_space(3))) void*)(lb + 16 * 32), 16, 0, 0);
    };

    int nk = Keff / 32;
    stage(0, 0);
    stage(1, 1);
    int rdsw = (lg ^ ((li >> 1) & 3)) * 8;
    for (int kt = 0; kt < nk; ++kt) {
        int buf = kt % 3;
        if (kt + 1 < nk) asm volatile("s_waitcnt vmcnt(4)" ::: "memory");
        else             asm volatile("s_waitcnt vmcnt(0)" ::: "memory");
        asm volatile("s_barrier" ::: "memory");
        __builtin_amdgcn_sched_barrier(0);
        bf16x8 af[4], bfr[4];
        #pragma unroll
        for (int i = 0; i < 4; ++i) {
            af[i] = *reinterpret_cast<const bf16x8*>(&As[buf][(wm + i * 16 + li) * 32 + rdsw]);
            bfr[i] = *reinterpret_cast<const bf16x8*>(&Bs[buf][(wn + i * 16 + li) * 32 + rdsw]);
        }
        __builtin_amdgcn_s_setprio(1);
        #pragma unroll
        for (int mi = 0; mi < 4; ++mi)
            #pragma unroll
            for (int ni = 0; ni < 4; ++ni)
                acc[mi][ni] = __builtin_amdgcn_mfma_f32_16x16x32_bf16(af[mi], bfr[ni], acc[mi][ni], 0, 0, 0);
        __builtin_amdgcn_s_setprio(0);
        if (kt + 2 < nk) stage((kt + 2) % 3, kt + 2);
    }

    #pragma unroll
    for (int mi = 0; mi < 4; ++mi) {
        #pragma unroll
        for (int r = 0; r < 4; ++r) {
            int row = m0 + wm + mi * 16 + lg * 4 + r;
            #pragma unroll
            for (int ni = 0; ni < 4; ++ni) {
                int col = n0 + wn + ni * 16 + li;
                if (EPI == EPI_RESK) {
                    float v = acc[mi][ni][r] + (split == 0 ? bias[col] : 0.f);
                    atomicAdd(&outf[(size_t)row * N + col], v);
                } else {
                    float v = acc[mi][ni][r] + bias[col];
                    if (EPI == EPI_GELU) outh[(size_t)row * N + col] = f2bf(gelu_f(v));
                    if (EPI == EPI_RES)  outf[(size_t)row * N + col] = res[(size_t)row * N + col] + v;
                    if (EPI == EPI_QKV) {
                        int which = col / 768;
                        int c2 = col - which * 768;
                        outh[(size_t)which * (8192 * 768) + (size_t)row * 768 + c2] = f2bf(v);
                    }
                }
            }
        }
    }
}

// ---------------- flash attention v9: K staged via global_load_lds ---------
// grid (8, 12, 8); 4 waves; wave w owns q-rows [qt*128 + w*32, +32) as 2 frags.
// K double-buffered in LDS (DMA, no VGPR roundtrip -> no r5 spill). The
// existing per-iteration __syncthreads drains vmcnt before s_barrier, so the
// K-DMA issued at iteration jt is guaranteed landed before iteration jt+1
// reads it -- no extra sync. K LDS reads use a chunk XOR swizzle
// (stored[row][cc] = G[row][(cc&4)|((cc&3)^(row&3))]) -> 4-way residual.
// LDS total = 18432(Vt) + 18432(P) + 16384(Ks) = 53248 B -> 3 blocks/CU.
__launch_bounds__(256, 3)
__global__ void flash_attn(const ushort* __restrict__ q, const ushort* __restrict__ k,
                           const ushort* __restrict__ v, ushort* __restrict__ o) {
    int flat = blockIdx.x + 8 * (blockIdx.y + 12 * blockIdx.z);
    flat = (flat & 7) * 96 + (flat >> 3);
    int qt = flat & 7;
    int rem = flat >> 3;
    int h = rem % 12;
    int b = rem / 12;

    int t = threadIdx.x, w = t >> 6, l = t & 63;
    int lg = l >> 4, li = l & 15;

    __shared__ __align__(16) ushort Vt[2][64][72];  // V^T tile, stride 144B
    __shared__ __align__(16) ushort P[4][32][72];   // per-wave P[q][kv]
    __shared__ __align__(16) ushort Ks[2][64 * 64]; // K tile, chunk-swizzled

    const size_t hoff = (size_t)h * 64;
    const size_t bbase = (size_t)b * 1024 * 768;
    const ushort* kbase = &k[bbase + hoff];

    bf16x8 qf[2][2];
    #pragma unroll
    for (int f = 0; f < 2; ++f) {
        int qrow = qt * 128 + w * 32 + f * 16 + li;
        const ushort* qp = &q[bbase + (size_t)qrow * 768 + hoff];
        qf[f][0] = *reinterpret_cast<const bf16x8*>(qp + lg * 8);
        qf[f][1] = *reinterpret_cast<const bf16x8*>(qp + 32 + lg * 8);
    }

    bf16x8 onesf;
    #pragma unroll
    for (int i = 0; i < 8; ++i) onesf[i] = (__bf16)1.0f;

    float m_[2][4];
    f32x4 oacc[2][4];
    f32x4 oell[2];
    #pragma unroll
    for (int f = 0; f < 2; ++f) {
        #pragma unroll
        for (int r = 0; r < 4; ++r) m_[f][r] = -1e30f;
        oell[f] = f32x4{0.f, 0.f, 0.f, 0.f};
        #pragma unroll
        for (int n = 0; n < 4; ++n) oacc[f][n] = f32x4{0.f, 0.f, 0.f, 0.f};
    }

    int vrow = t & 63;
    int vc = t >> 6;
    const ushort* vbase = &v[bbase + hoff];

    // K staging: 4 waves x 2 loads cover 64x64; dest linear chunks, source
    // column pre-swizzled so LDS holds stored[row][cc] = G[row][swz(cc,row)].
    auto stageK = [&](int kbuf, int jtile) {
        #pragma unroll
        for (int j = 0; j < 2; ++j) {
            int c = (w * 2 + j) * 64 + l;
            int krow = c >> 3, kcc = c & 7;
            int srcc = (kcc & 4) | ((kcc & 3) ^ (krow & 3));
            const ushort* src = &kbase[(size_t)(jtile * 64 + krow) * 768 + srcc * 8];
            __builtin_amdgcn_global_load_lds(
                (const __attribute__((address_space(1))) void*)src,
                (__attribute__((address_space(3))) void*)&Ks[kbuf][c * 8], 16, 0, 0);
        }
    };

    // prologue: K tile 0 + first V registers; barrier drains the DMA.
    stageK(0, 0);
    ushort8 vv0 = *reinterpret_cast<const ushort8*>(&vbase[(size_t)vrow * 768 + vc * 8]);
    ushort8 vv1 = *reinterpret_cast<const ushort8*>(&vbase[(size_t)vrow * 768 + (vc + 4) * 8]);
    __syncthreads();

    int kch = lg ^ (li & 3);   // swizzled read chunk (row&3 == li&3 for all jj)

    for (int jt = 0; jt < 16; ++jt) {
        int j0 = jt * 64, buf = jt & 1;
        #pragma unroll
        for (int i = 0; i < 8; ++i) Vt[buf][vc * 8 + i][vrow] = vv0[i];
        #pragma unroll
        for (int i = 0; i < 8; ++i) Vt[buf][(vc + 4) * 8 + i][vrow] = vv1[i];
        if (jt < 15) {
            vv0 = *reinterpret_cast<const ushort8*>(&vbase[(size_t)(j0 + 64 + vrow) * 768 + vc * 8]);
            vv1 = *reinterpret_cast<const ushort8*>(&vbase[(size_t)(j0 + 64 + vrow) * 768 + (vc + 4) * 8]);
            stageK(buf ^ 1, jt + 1);   // lands by this iteration's __syncthreads
        }
        // S = Q K^T / 8; K fragments from LDS (swizzled chunks)
        f32x4 s[2][4];
        __builtin_amdgcn_s_setprio(1);
        #pragma unroll
        for (int jj = 0; jj < 4; ++jj) {
            int krow = jj * 16 + li;
            bf16x8 kf0 = *reinterpret_cast<const bf16x8*>(&Ks[buf][krow * 64 + kch * 8]);
            bf16x8 kf1 = *reinterpret_cast<const bf16x8*>(&Ks[buf][krow * 64 + 32 + kch * 8]);
            #pragma unroll
            for (int f = 0; f < 2; ++f) {
                f32x4 a = {0.f, 0.f, 0.f, 0.f};
                a = __builtin_amdgcn_mfma_f32_16x16x32_bf16(qf[f][0], kf0, a, 0, 0, 0);
                a = __builtin_amdgcn_mfma_f32_16x16x32_bf16(qf[f][1], kf1, a, 0, 0, 0);
                s[f][jj] = a * 0.125f;
            }
        }
        __builtin_amdgcn_s_setprio(0);
        #pragma unroll
        for (int f = 0; f < 2; ++f) {
            float mt[4];
            #pragma unroll
            for (int r = 0; r < 4; ++r)
                mt[r] = fmaxf(fmaxf(s[f][0][r], s[f][1][r]), fmaxf(s[f][2][r], s[f][3][r]));
            #pragma unroll
            for (int r = 0; r < 4; ++r) {
                mt[r] = fmaxf(mt[r], __shfl_xor(mt[r], 1));
                mt[r] = fmaxf(mt[r], __shfl_xor(mt[r], 2));
                mt[r] = fmaxf(mt[r], __shfl_xor(mt[r], 4));
                mt[r] = fmaxf(mt[r], __shfl_xor(mt[r], 8));
            }
            bool need = (mt[0] > m_[f][0] + 8.f) | (mt[1] > m_[f][1] + 8.f) |
                        (mt[2] > m_[f][2] + 8.f) | (mt[3] > m_[f][3] + 8.f);
            if (__any(need)) {
                #pragma unroll
                for (int r = 0; r < 4; ++r) {
                    float mn = fmaxf(m_[f][r], mt[r]);
                    float al = __expf(m_[f][r] - mn);
                    m_[f][r] = mn;
                    #pragma unroll
                    for (int n = 0; n < 4; ++n) oacc[f][n][r] *= al;
                    oell[f][r] *= al;
                }
            }
            #pragma unroll
            for (int jj = 0; jj < 4; ++jj)
                #pragma unroll
                for (int r = 0; r < 4; ++r)
                    P[w][f * 16 + lg * 4 + r][jj * 16 + li] = f2bf(__expf(s[f][jj][r] - m_[f][r]));
        }
        __syncthreads();   // drains K-DMA for jt+1; orders Vt/P
        bf16x8 pf[2][2];
        #pragma unroll
        for (int f = 0; f < 2; ++f) {
            pf[f][0] = *reinterpret_cast<const bf16x8*>(&P[w][f * 16 + li][lg * 8]);
            pf[f][1] = *reinterpret_cast<const bf16x8*>(&P[w][f * 16 + li][32 + lg * 8]);
        }
        __builtin_amdgcn_s_setprio(1);
        #pragma unroll
        for (int f = 0; f < 2; ++f) {
            oell[f] = __builtin_amdgcn_mfma_f32_16x16x32_bf16(pf[f][0], onesf, oell[f], 0, 0, 0);
            oell[f] = __builtin_amdgcn_mfma_f32_16x16x32_bf16(pf[f][1], onesf, oell[f], 0, 0, 0);
        }
        #pragma unroll
        for (int n = 0; n < 4; ++n) {
            bf16x8 vf0 = *reinterpret_cast<const bf16x8*>(&Vt[buf][n * 16 + li][lg * 8]);
            bf16x8 vf1 = *reinterpret_cast<const bf16x8*>(&Vt[buf][n * 16 + li][32 + lg * 8]);
            #pragma unroll
            for (int f = 0; f < 2; ++f) {
                oacc[f][n] = __builtin_amdgcn_mfma_f32_16x16x32_bf16(pf[f][0], vf0, oacc[f][n], 0, 0, 0);
                oacc[f][n] = __builtin_amdgcn_mfma_f32_16x16x32_bf16(pf[f][1], vf1, oacc[f][n], 0, 0, 0);
            }
        }
        __builtin_amdgcn_s_setprio(0);
    }
    #pragma unroll
    for (int f = 0; f < 2; ++f)
        #pragma unroll
        for (int n = 0; n < 4; ++n)
            #pragma unroll
            for (int r = 0; r < 4; ++r) {
                int row = qt * 128 + w * 32 + f * 16 + lg * 4 + r;
                o[bbase + (size_t)row * 768 + hoff + n * 16 + li] = f2bf(oacc[f][n][r] / oell[f][r]);
            }
}

// ---------------------------------------------------------------------------
extern "C" void kernel_launch(void* const* d_in, const int* in_sizes, int n_in,
                              void* d_out, int out_size, void* d_ws, size_t ws_size,
                              hipStream_t stream) {
    const float* x = (const float*)d_in[0];
    const float* dp_w = (const float*)d_in[1];
    const float* dp_b = (const float*)d_in[2];
    const float* se_w1 = (const float*)d_in[3];
    const float* se_b1 = (const float*)d_in[4];
    const float* se_w2 = (const float*)d_in[5];
    const float* se_b2 = (const float*)d_in[6];
    const float* wq = (const float*)d_in[7];  const float* bq = (const float*)d_in[8];
    const float* wk = (const float*)d_in[9];  const float* bk = (const float*)d_in[10];
    const float* wv = (const float*)d_in[11]; const float* bv = (const float*)d_in[12];
    const float* wo = (const float*)d_in[13]; const float* bo = (const float*)d_in[14];
    const float* gw1 = (const float*)d_in[15]; const float* gb1 = (const float*)d_in[16];
    const float* gw2 = (const float*)d_in[17]; const float* gb2 = (const float*)d_in[18];
    const float* n1g = (const float*)d_in[19]; const float* n1b = (const float*)d_in[20];
    const float* n2g = (const float*)d_in[21]; const float* n2b = (const float*)d_in[22];
    float* out = (float*)d_out;

    constexpr size_t SZ_ACT = (size_t)8192 * 768 * 2;  // bytes per bf16 activation
    char* W = (char*)d_ws;
    ushort* xb = (ushort*)(W);                  // bf16 x; later reused as xn
    ushort* q_ = (ushort*)(W + SZ_ACT);
    ushort* k_ = (ushort*)(W + 2 * SZ_ACT);
    ushort* v_ = (ushort*)(W + 3 * SZ_ACT);
    ushort* o_ = (ushort*)(W + 4 * SZ_ACT);
    ushort* hsp = q_;
    ushort* hff = q_;
    ushort* wqt = (ushort*)(W + 5 * SZ_ACT);    // contiguous qkv weight [2304][768]
    ushort* wkt = wqt + (size_t)768 * 768;
    ushort* wvt = wkt + (size_t)768 * 768;
    ushort* wot = wvt + (size_t)768 * 768;
    ushort* sw2t = wot + (size_t)768 * 768;
    ushort* g1t = sw2t + (size_t)768 * 768;
    ushort* g2t = g1t + (size_t)768 * 3072;
    float* sqv = (float*)(g2t + (size_t)3072 * 768);
    float* meanv = sqv + 8192;
    float* Avec = meanv + 8192;
    float* Cvec = Avec + 768;
    float* bqkv = Cvec + 768;                   // concat bias [2304]

    // fused prologue: 7 transposes + rowstat + precomp + meanv=0 + bqkv concat
    prep_all<<<15716, 256, 0, stream>>>(se_w2, sw2t, wq, wqt, wk, wkt, wv, wvt,
                                        wo, wot, gw1, g1t, gw2, g2t,
                                        x, xb, sqv, bq, bk, bv, bqkv, meanv,
                                        dp_w, dp_b, se_w1, se_b1, Avec, Cvec);

    // Gram -> distance row-sums (batch-per-XCD, L2-resident)
    gemm_bt<EPI_GRAM, 128><<<dim3(8, 8, 8), 256, 0, stream>>>(xb, xb, 1024, 1024, 768,
                                                              nullptr, nullptr, nullptr, nullptr, sqv, meanv);
    hgen<<<8192, 256, 0, stream>>>(meanv, Avec, Cvec, hsp);
    // x = x + h @ se_w2 + se_b2  -> d_out (fp32 residual stream)
    gemm4<EPI_RES><<<dim3(64, 6), 256, 0, stream>>>(hsp, sw2t, 8192, 768, 768,
                                                    se_b2, x, out, nullptr);
    // attention block
    lnorm<<<8192, 256, 0, stream>>>(out, n1g, n1b, xb);
    gemm4<EPI_QKV><<<dim3(64, 18), 256, 0, stream>>>(xb, wqt, 8192, 2304, 768,
                                                     bqkv, nullptr, nullptr, q_);
    flash_attn<<<dim3(8, 12, 8), 256, 0, stream>>>(q_, k_, v_, o_);
    gemm4<EPI_RES><<<dim3(64, 6), 256, 0, stream>>>(o_, wot, 8192, 768, 768,
                                                    bo, out, out, nullptr);
    // FFN block
    lnorm<<<8192, 256, 0, stream>>>(out, n2g, n2b, xb);
    gemm4<EPI_GELU><<<dim3(64, 24), 256, 0, stream>>>(xb, g1t, 8192, 3072, 768,
                                                      gb1, nullptr, nullptr, hff);
    // FFN2 split-K=2: atomicAdd partials onto out (already holds residual)
    gemm4<EPI_RESK><<<dim3(64, 6, 2), 256, 0, stream>>>(hff, g2t, 8192, 768, 3072,
                                                        gb2, nullptr, out, nullptr);
}